// Round 3
// baseline (598.183 us; speedup 1.0000x reference)
//
#include <hip/hip_runtime.h>
#include <hip/hip_bf16.h>

// GCN_55602646614506 — round 3: dispatch-count attack (23 -> 11) + adjacency fusion.
// r2 post-mortem: content model ~290us vs measured 525us -> ~235us in launch gaps +
// short-K overhead. Changes: prep_mega (4-in-1), mlp_head (sp1+sp2 in-LDS chain),
// adj_fused (register A-build from H1/N1/u2, fat acc, partial-plane epilogue: no hdn
// buffer, no atomics, no memset), msgln merged with ping-pong buffers.

typedef __attribute__((ext_vector_type(4))) float  f32x4;
typedef __attribute__((ext_vector_type(8))) __bf16 bf16x8;
typedef __attribute__((ext_vector_type(4))) __bf16 bf16x4;

#define FEPS 1e-10f
#define LNEPS 1e-5f
#define GAMA_F 0.9f

__device__ __forceinline__ void gload16(const void* g, void* l) {
  __builtin_amdgcn_global_load_lds(
      (const __attribute__((address_space(1))) void*)g,
      (__attribute__((address_space(3))) void*)l, 16, 0, 0);
}

__device__ __forceinline__ float read_dim(const void* p) {
  int iv = *(const int*)p;
  if (iv > 0 && iv < (1 << 20)) return (float)iv;
  return *(const float*)p;
}

// ---------------- prep_mega: weight transposes + small prep + init + spatial ----------------
// grid 3072 x 256
__global__ void prep_mega(const float* __restrict__ w1, const float* __restrict__ w2,
                          const float* __restrict__ w3, const float* __restrict__ spw3,
                          const float* __restrict__ spw1, const float* __restrict__ spw2,
                          const float* __restrict__ b3,
                          const float* __restrict__ node_in,
                          const float* __restrict__ coords,
                          const void* __restrict__ imh, const void* __restrict__ imw,
                          __bf16* __restrict__ W1at, __bf16* __restrict__ W1bt,
                          __bf16* __restrict__ W2t, __bf16* __restrict__ W3t,
                          __bf16* __restrict__ SpW3t,
                          __bf16* __restrict__ SpW1t, __bf16* __restrict__ SpW2t,
                          float* __restrict__ b3s,
                          float* __restrict__ node_f, __bf16* __restrict__ node_b,
                          float* __restrict__ hn_f, __bf16* __restrict__ hn_b,
                          __bf16* __restrict__ f36) {
  __shared__ float tile[64][65];
  const int b = blockIdx.x, t = threadIdx.x;
  const int tc = t & 63, tr = t >> 6;
  if (b < 256) {
    const int c = b >> 4, d0 = (b & 15) << 6;
    #pragma unroll
    for (int pass = 0; pass < 2; ++pass) {
      const float* src = w1 + (size_t)c * 131072 + (size_t)(d0 + pass * 1024) * 64;
      __bf16* dst = pass ? W1bt : W1at;
      if (pass) __syncthreads();
      #pragma unroll
      for (int q = 0; q < 16; ++q) {
        int dd = q * 4 + tr;
        tile[dd][tc] = src[dd * 64 + tc];
      }
      __syncthreads();
      #pragma unroll
      for (int q = 0; q < 16; ++q) {
        int kk = q * 4 + tr;
        dst[(size_t)(c * 64 + kk) * 1024 + d0 + tc] = (__bf16)tile[tc][kk];
      }
    }
  } else if (b < 512) {
    const int bb = b - 256, c = bb >> 4, s0 = (bb & 15) << 6;
    const float* src = w2 + (size_t)c * 65536 + (size_t)s0 * 64;
    #pragma unroll
    for (int q = 0; q < 16; ++q) {
      int ss = q * 4 + tr;
      tile[ss][tc] = src[ss * 64 + tc];
    }
    __syncthreads();
    #pragma unroll
    for (int q = 0; q < 16; ++q) {
      int kk = q * 4 + tr;
      W2t[(size_t)(c * 64 + kk) * 1024 + s0 + tc] = (__bf16)tile[tc][kk];
    }
  } else if (b < 768) {
    const int bb = b - 512, c = bb >> 4, o0 = (bb & 15) << 6;
    const float* src = w3 + (size_t)c * 65536;
    #pragma unroll
    for (int q = 0; q < 16; ++q) {
      int kk = q * 4 + tr;
      tile[kk][tc] = src[kk * 1024 + o0 + tc];
    }
    __syncthreads();
    #pragma unroll
    for (int q = 0; q < 16; ++q) {
      int oo = q * 4 + tr;
      W3t[(size_t)(o0 + oo) * 1024 + c * 64 + tc] = (__bf16)tile[tc][oo];
    }
  } else if (b < 832) {
    const int bb = b - 768, o0 = (bb >> 2) << 6, k0 = (bb & 3) << 6;
    #pragma unroll
    for (int q = 0; q < 16; ++q) {
      int kk = q * 4 + tr;
      tile[kk][tc] = spw3[(size_t)(k0 + kk) * 1024 + o0 + tc];
    }
    __syncthreads();
    #pragma unroll
    for (int q = 0; q < 16; ++q) {
      int oo = q * 4 + tr;
      SpW3t[(size_t)(o0 + oo) * 256 + k0 + tc] = (__bf16)tile[tc][oo];
    }
  } else if (b < 960) {
    int gid = (b - 832) * 256 + t;              // 0..32767
    if (gid < 8192) {
      int n = gid >> 6, k = gid & 63;
      SpW1t[gid] = (k < 36) ? (__bf16)spw1[k * 128 + n] : (__bf16)0.f;
    }
    {
      int n = gid >> 7, k = gid & 127;
      SpW2t[gid] = (__bf16)spw2[k * 256 + n];
    }
    if (gid < 1024) {
      float s = 0.f;
      for (int cc = 0; cc < 16; ++cc) s += b3[cc * 1024 + gid];
      b3s[gid] = s;
    }
  } else if (b < 3008) {
    int gid = (b - 960) * 256 + t;              // 0..524287
    float v = node_in[gid];
    node_f[gid] = v;
    node_b[gid] = (__bf16)v;
    if (gid < 32 * 1024) { hn_f[gid] = v; hn_b[gid] = (__bf16)v; }
  } else {
    int p = (b - 3008) * 256 + t;               // 0..16383
    int i = p >> 9, j = p & 511;
    float H = read_dim(imh), W = read_dim(imw);
    f32x4 b1 = ((const f32x4*)coords)[i];
    f32x4 b2 = ((const f32x4*)coords)[j];
    float c1x = (b1[0] + b1[2]) * 0.5f, c1y = (b1[1] + b1[3]) * 0.5f;
    float c2x = (b2[0] + b2[2]) * 0.5f, c2y = (b2[1] + b2[3]) * 0.5f;
    float b1w = b1[2] - b1[0], b1h = b1[3] - b1[1];
    float b2w = b2[2] - b2[0], b2h = b2[3] - b2[1];
    float dx = fabsf(c2x - c1x) / (b1w + FEPS);
    float dy = fabsf(c2y - c1y) / (b1h + FEPS);
    float ltx = fmaxf(b1[0], b2[0]), lty = fmaxf(b1[1], b2[1]);
    float rbx = fminf(b1[2], b2[2]), rby = fminf(b1[3], b2[3]);
    float inter = fmaxf(rbx - ltx, 0.f) * fmaxf(rby - lty, 0.f);
    float a1 = b1w * b1h, a2 = b2w * b2h;
    float iou = inter / (a1 + a2 - inter);
    float f[18];
    f[0] = c1x / W;  f[1] = c1y / H;  f[2] = c2x / W;  f[3] = c2y / H;
    f[4] = b1w / W;  f[5] = b1h / H;  f[6] = b2w / W;  f[7] = b2h / H;
    f[8] = a1 / (H * W); f[9] = a2 / (H * W); f[10] = a2 / (a1 + FEPS);
    f[11] = b1w / (b1h + FEPS); f[12] = b2w / (b2h + FEPS); f[13] = iou;
    f[14] = (c2x > c1x) ? dx : 0.f; f[15] = (c2x < c1x) ? dx : 0.f;
    f[16] = (c2y > c1y) ? dy : 0.f; f[17] = (c2y < c1y) ? dy : 0.f;
    __bf16 o[64];
    #pragma unroll
    for (int q = 0; q < 18; ++q) { o[q] = (__bf16)f[q]; o[18 + q] = (__bf16)logf(f[q] + FEPS); }
    #pragma unroll
    for (int q = 36; q < 64; ++q) o[q] = (__bf16)0.f;
    bf16x8* dst = (bf16x8*)(f36 + (size_t)p * 64);
    #pragma unroll
    for (int q = 0; q < 8; ++q) dst[q] = *(bf16x8*)&o[q * 8];
  }
}

// ---------------- mlp_head: sp1 + sp2 fused, per-128-row block ----------------
// grid 128 x 256; LDS: f36 16KB + W1 16KB + sp1 32KB + W2 64KB = 128KB
__global__ __launch_bounds__(256)
void mlp_head(const __bf16* __restrict__ f36, const __bf16* __restrict__ SpW1t,
              const __bf16* __restrict__ SpW2t, const float* __restrict__ b1,
              const float* __restrict__ b2, __bf16* __restrict__ sp2out) {
  __shared__ __align__(16) __bf16 Af[128 * 64];   // f36 tile
  __shared__ __align__(16) __bf16 W1s[128 * 64];
  __shared__ __align__(16) __bf16 S1[128 * 128];  // sp1 tile
  __shared__ __align__(16) __bf16 W2s[256 * 128];
  const int t = threadIdx.x;
  const int lane = t & 63, wv = t >> 6;
  const int wr = wv >> 1, wc = wv & 1;
  const int lr = lane & 15, lg = lane >> 4;
  const int m0 = blockIdx.x * 128;

  // flat staging (same layout global->LDS)
  #pragma unroll
  for (int cc = 0; cc < 4; ++cc)                  // Af: 16KB = 16 chunks
    gload16(f36 + (size_t)m0 * 64 + (wv * 4 + cc) * 512 + lane * 8, &Af[(wv * 4 + cc) * 512 + lane * 8]);
  #pragma unroll
  for (int cc = 0; cc < 4; ++cc)
    gload16(SpW1t + (wv * 4 + cc) * 512 + lane * 8, &W1s[(wv * 4 + cc) * 512 + lane * 8]);
  #pragma unroll
  for (int cc = 0; cc < 16; ++cc)                 // W2s: 64KB = 64 chunks
    gload16(SpW2t + (wv * 16 + cc) * 512 + lane * 8, &W2s[(wv * 16 + cc) * 512 + lane * 8]);
  __syncthreads();

  // sp1 = relu(f36 @ W1^T + b1): M=128 N=128 K=64
  {
    f32x4 acc[4][4] = {};
    #pragma unroll
    for (int ks = 0; ks < 2; ++ks) {
      bf16x8 af[4], bf[4];
      #pragma unroll
      for (int mi = 0; mi < 4; ++mi)
        af[mi] = *(const bf16x8*)&Af[(wr * 64 + mi * 16 + lr) * 64 + ks * 32 + lg * 8];
      #pragma unroll
      for (int ni = 0; ni < 4; ++ni)
        bf[ni] = *(const bf16x8*)&W1s[(wc * 64 + ni * 16 + lr) * 64 + ks * 32 + lg * 8];
      #pragma unroll
      for (int mi = 0; mi < 4; ++mi)
        #pragma unroll
        for (int ni = 0; ni < 4; ++ni)
          acc[mi][ni] = __builtin_amdgcn_mfma_f32_16x16x32_bf16(af[mi], bf[ni], acc[mi][ni], 0, 0, 0);
    }
    __syncthreads();   // Af/W1s reads done (S1 distinct, but keep order clean)
    #pragma unroll
    for (int mi = 0; mi < 4; ++mi)
      #pragma unroll
      for (int r = 0; r < 4; ++r) {
        int R = wr * 64 + mi * 16 + lg * 4 + r;
        #pragma unroll
        for (int ni = 0; ni < 4; ++ni) {
          int Cc = wc * 64 + ni * 16 + lr;
          S1[R * 128 + Cc] = (__bf16)fmaxf(acc[mi][ni][r] + b1[Cc], 0.f);
        }
      }
  }
  __syncthreads();

  // sp2 = relu(sp1 @ W2^T + b2): M=128 N=256 K=128
  {
    f32x4 acc[4][8] = {};
    #pragma unroll
    for (int ks = 0; ks < 4; ++ks) {
      bf16x8 af[4];
      #pragma unroll
      for (int mi = 0; mi < 4; ++mi)
        af[mi] = *(const bf16x8*)&S1[(wr * 64 + mi * 16 + lr) * 128 + ks * 32 + lg * 8];
      #pragma unroll
      for (int ni = 0; ni < 8; ++ni) {
        bf16x8 bf = *(const bf16x8*)&W2s[(wc * 128 + ni * 16 + lr) * 128 + ks * 32 + lg * 8];
        #pragma unroll
        for (int mi = 0; mi < 4; ++mi)
          acc[mi][ni] = __builtin_amdgcn_mfma_f32_16x16x32_bf16(af[mi], bf, acc[mi][ni], 0, 0, 0);
      }
    }
    #pragma unroll
    for (int mi = 0; mi < 4; ++mi)
      #pragma unroll
      for (int r = 0; r < 4; ++r) {
        int R = m0 + wr * 64 + mi * 16 + lg * 4 + r;
        #pragma unroll
        for (int ni = 0; ni < 8; ++ni) {
          int Cc = wc * 128 + ni * 16 + lr;
          sp2out[(size_t)R * 256 + Cc] = (__bf16)fmaxf(acc[mi][ni][r] + b2[Cc], 0.f);
        }
      }
  }
}

// ---------------- generic MFMA GEMM (m97 structure) for spb / u2 ----------------
template <int EPI>  // 0 relu+bias->bf16; 1 bias->bf16
__global__ __launch_bounds__(256)
void gemm_bt(const __bf16* __restrict__ A, const __bf16* __restrict__ Bt,
             const float* __restrict__ bias, void* __restrict__ C,
             int M, int N, int K) {
  __shared__ __align__(16) __bf16 As[128 * 64];
  __shared__ __align__(16) __bf16 Bs[128 * 64];
  const int t = threadIdx.x;
  const int lane = t & 63, wv = t >> 6;
  const int wr = wv >> 1, wc = wv & 1;
  const int lr = lane & 15, lg = lane >> 4;
  const int lrow = lane >> 3, lcol = (lane & 7) << 3;
  const int m0 = blockIdx.x * 128, n0 = blockIdx.y * 128;

  f32x4 acc[4][4] = {};
  const int nkt = K >> 6;
  for (int kt = 0; kt < nkt; ++kt) {
    const int k0 = kt << 6;
    #pragma unroll
    for (int it = 0; it < 4; ++it) {
      const int rbase = wv * 32 + it * 8;
      gload16(A + (size_t)(m0 + rbase + lrow) * K + k0 + lcol, &As[rbase * 64]);
      gload16(Bt + (size_t)(n0 + rbase + lrow) * K + k0 + lcol, &Bs[rbase * 64]);
    }
    __syncthreads();
    #pragma unroll
    for (int ks = 0; ks < 2; ++ks) {
      bf16x8 af[4], bfr[4];
      #pragma unroll
      for (int mi = 0; mi < 4; ++mi)
        af[mi] = *(const bf16x8*)&As[(wr * 64 + mi * 16 + lr) * 64 + ks * 32 + lg * 8];
      #pragma unroll
      for (int ni = 0; ni < 4; ++ni)
        bfr[ni] = *(const bf16x8*)&Bs[(wc * 64 + ni * 16 + lr) * 64 + ks * 32 + lg * 8];
      #pragma unroll
      for (int mi = 0; mi < 4; ++mi)
        #pragma unroll
        for (int ni = 0; ni < 4; ++ni)
          acc[mi][ni] = __builtin_amdgcn_mfma_f32_16x16x32_bf16(af[mi], bfr[ni], acc[mi][ni], 0, 0, 0);
    }
    __syncthreads();
  }
  #pragma unroll
  for (int mi = 0; mi < 4; ++mi)
    #pragma unroll
    for (int r = 0; r < 4; ++r) {
      int R = m0 + wr * 64 + mi * 16 + lg * 4 + r;
      #pragma unroll
      for (int ni = 0; ni < 4; ++ni) {
        int Cc = n0 + wc * 64 + ni * 16 + lr;
        float v = acc[mi][ni][r] + bias[Cc];
        if constexpr (EPI == 0) v = fmaxf(v, 0.f);
        ((__bf16*)C)[(size_t)R * N + Cc] = (__bf16)v;
      }
    }
}

// ---------------- H1 + N1 (32x128 tiles, grid (17,8)) ----------------
__global__ __launch_bounds__(256)
void gemm_u1(const __bf16* __restrict__ hn_b, const __bf16* __restrict__ node_b,
             const __bf16* __restrict__ W1at, const __bf16* __restrict__ W1bt,
             const float* __restrict__ b1, float* __restrict__ H1, float* __restrict__ N1) {
  __shared__ __align__(16) __bf16 As[32 * 64];
  __shared__ __align__(16) __bf16 Bs[128 * 64];
  const int t = threadIdx.x;
  const int lane = t & 63, wv = t >> 6;
  const int wr = wv >> 1, wc = wv & 1;
  const int lr = lane & 15, lg = lane >> 4;
  const int lrow = lane >> 3, lcol = (lane & 7) << 3;
  const bool isH = (blockIdx.x == 0);
  const __bf16* Ap = isH ? hn_b : node_b + (size_t)(blockIdx.x - 1) * 32 * 1024;
  const __bf16* Bp = isH ? W1at : W1bt;
  const int n0 = blockIdx.y * 128;

  f32x4 acc[4] = {};
  for (int kt = 0; kt < 16; ++kt) {
    const int k0 = kt << 6;
    gload16(Ap + (size_t)(wv * 8 + lrow) * 1024 + k0 + lcol, &As[(wv * 8) * 64]);
    #pragma unroll
    for (int it = 0; it < 4; ++it) {
      const int rbase = wv * 32 + it * 8;
      gload16(Bp + (size_t)(n0 + rbase + lrow) * 1024 + k0 + lcol, &Bs[rbase * 64]);
    }
    __syncthreads();
    #pragma unroll
    for (int ks = 0; ks < 2; ++ks) {
      bf16x8 af = *(const bf16x8*)&As[(wr * 16 + lr) * 64 + ks * 32 + lg * 8];
      #pragma unroll
      for (int ni = 0; ni < 4; ++ni) {
        bf16x8 bfr = *(const bf16x8*)&Bs[(wc * 64 + ni * 16 + lr) * 64 + ks * 32 + lg * 8];
        acc[ni] = __builtin_amdgcn_mfma_f32_16x16x32_bf16(af, bfr, acc[ni], 0, 0, 0);
      }
    }
    __syncthreads();
  }
  #pragma unroll
  for (int ni = 0; ni < 4; ++ni)
    #pragma unroll
    for (int r = 0; r < 4; ++r) {
      int R = wr * 16 + lg * 4 + r;
      int Cc = n0 + wc * 64 + ni * 16 + lr;
      float v = acc[ni][r];
      if (isH) H1[(size_t)R * 1024 + Cc] = v + b1[Cc];
      else     N1[((size_t)(blockIdx.x - 1) * 32 + R) * 1024 + Cc] = v;
    }
}

// ---------------- adj_fused: register A-build + GEMM + adjacency-dot epilogue ----------------
// grid (128, 4): block = 128 rows x 256 cols, full K=1024. No hdn buffer, no atomics.
__global__ __launch_bounds__(256, 2)
void adj_fused(const __bf16* __restrict__ u2, const float* __restrict__ H1,
               const float* __restrict__ N1, const __bf16* __restrict__ W3t,
               const float* __restrict__ b3s, const float* __restrict__ adjw,
               float* __restrict__ adjpre4) {
  __shared__ __align__(16) __bf16 Bs[256 * 64];   // 32KB
  __shared__ float redbuf[2][128];
  const int t = threadIdx.x;
  const int lane = t & 63, wv = t >> 6;
  const int wr = wv >> 1, wc = wv & 1;
  const int lr = lane & 15, lg = lane >> 4;
  const int lrow = lane >> 3, lcol = (lane & 7) << 3;
  const int m0 = blockIdx.x * 128;
  const int h = blockIdx.y;
  const int c0 = h * 256;
  const int i_h = m0 >> 9;
  const int j0 = m0 & 511;

  f32x4 acc[2][4][4] = {};
  for (int kt = 0; kt < 16; ++kt) {
    const int k0 = kt << 6;
    // stage B (async, 32KB): 32 chunks of 8 rows
    #pragma unroll
    for (int it = 0; it < 8; ++it) {
      const int rbase = wv * 64 + it * 8;
      gload16(W3t + (size_t)(c0 + rbase + lrow) * 1024 + k0 + lcol, &Bs[rbase * 64]);
    }
    // build A fragments in registers (overlaps the gload latency)
    float hk[2][8];
    #pragma unroll
    for (int ks = 0; ks < 2; ++ks) {
      const float* hp = H1 + (size_t)i_h * 1024 + k0 + ks * 32 + lg * 8;
      f32x4 a0 = *(const f32x4*)hp;
      f32x4 a1 = *(const f32x4*)(hp + 4);
      #pragma unroll
      for (int e = 0; e < 4; ++e) { hk[ks][e] = a0[e]; hk[ks][4 + e] = a1[e]; }
    }
    bf16x8 af[4][2];
    #pragma unroll
    for (int mi = 0; mi < 4; ++mi) {
      const int ro = wr * 64 + mi * 16 + lr;
      const __bf16* up = u2 + (size_t)(m0 + ro) * 1024 + k0;
      const float* np = N1 + (size_t)(j0 + ro) * 1024 + k0;
      #pragma unroll
      for (int ks = 0; ks < 2; ++ks) {
        bf16x8 u = *(const bf16x8*)(up + ks * 32 + lg * 8);
        f32x4 n0v = *(const f32x4*)(np + ks * 32 + lg * 8);
        f32x4 n1v = *(const f32x4*)(np + ks * 32 + lg * 8 + 4);
        bf16x8 o;
        #pragma unroll
        for (int e = 0; e < 4; ++e) {
          o[e]     = (__bf16)fmaxf((hk[ks][e] + n0v[e]) * (float)u[e], 0.f);
          o[4 + e] = (__bf16)fmaxf((hk[ks][4 + e] + n1v[e]) * (float)u[4 + e], 0.f);
        }
        af[mi][ks] = o;
      }
    }
    __syncthreads();                              // drains gloads
    #pragma unroll
    for (int nt = 0; nt < 2; ++nt)
      #pragma unroll
      for (int ks = 0; ks < 2; ++ks) {
        bf16x8 bfr[4];
        #pragma unroll
        for (int ni = 0; ni < 4; ++ni)
          bfr[ni] = *(const bf16x8*)&Bs[(nt * 128 + wc * 64 + ni * 16 + lr) * 64 + ks * 32 + lg * 8];
        #pragma unroll
        for (int mi = 0; mi < 4; ++mi)
          #pragma unroll
          for (int ni = 0; ni < 4; ++ni)
            acc[nt][mi][ni] = __builtin_amdgcn_mfma_f32_16x16x32_bf16(af[mi][ks], bfr[ni], acc[nt][mi][ni], 0, 0, 0);
      }
    __syncthreads();                              // Bs reads done before next stage
  }

  // adjacency-dot epilogue: partial over this block's 256 cols
  float b3v[2][4], awv[2][4];
  #pragma unroll
  for (int nt = 0; nt < 2; ++nt)
    #pragma unroll
    for (int ni = 0; ni < 4; ++ni) {
      int Cc = c0 + nt * 128 + wc * 64 + ni * 16 + lr;
      b3v[nt][ni] = b3s[Cc];
      awv[nt][ni] = adjw[Cc];
    }
  #pragma unroll
  for (int mi = 0; mi < 4; ++mi)
    #pragma unroll
    for (int r = 0; r < 4; ++r) {
      float s = 0.f;
      #pragma unroll
      for (int nt = 0; nt < 2; ++nt)
        #pragma unroll
        for (int ni = 0; ni < 4; ++ni)
          s += fmaxf(acc[nt][mi][ni][r] + b3v[nt][ni], 0.f) * awv[nt][ni];
      s += __shfl_xor(s, 1);
      s += __shfl_xor(s, 2);
      s += __shfl_xor(s, 4);
      s += __shfl_xor(s, 8);
      if (lr == 0)
        redbuf[wc][wr * 64 + mi * 16 + lg * 4 + r] = s;
    }
  __syncthreads();
  if (t < 128)
    adjpre4[(size_t)h * 16384 + m0 + t] = redbuf[0][t] + redbuf[1][t];
}

// ---------------- msg + LN merged (ping-pong buffers) ----------------
// grid 544: rows 0..31 = human, 32..543 = node (j = row-32)
__global__ void msgln(const float* __restrict__ adjpre4, const float* __restrict__ adjb,
                      const float* __restrict__ node_in_f, const float* __restrict__ hn_in_f,
                      const float* __restrict__ lno_g, const float* __restrict__ lno_b,
                      const float* __restrict__ lnh_g, const float* __restrict__ lnh_b,
                      float* __restrict__ node_out_f, float* __restrict__ hn_out_f,
                      __bf16* __restrict__ node_bb, __bf16* __restrict__ hn_bb) {
  __shared__ float sbuf[4];
  const int row = blockIdx.x, t = threadIdx.x;
  const float ab = adjb[0];
  const bool isH = row < 32;
  f32x4 msg = {0.f, 0.f, 0.f, 0.f};
  if (isH) {
    const int i = row;
    for (int j = 0; j < 512; j += 4) {
      f32x4 a0 = *(const f32x4*)(adjpre4 + i * 512 + j);
      f32x4 a1 = *(const f32x4*)(adjpre4 + 16384 + i * 512 + j);
      f32x4 a2 = *(const f32x4*)(adjpre4 + 32768 + i * 512 + j);
      f32x4 a3 = *(const f32x4*)(adjpre4 + 49152 + i * 512 + j);
      #pragma unroll
      for (int e = 0; e < 4; ++e) {
        float a = fmaxf(a0[e] + a1[e] + a2[e] + a3[e] + ab, 0.f);
        msg += a * ((const f32x4*)node_in_f)[(j + e) * 256 + t];
      }
    }
  } else {
    const int j = row - 32;
    for (int i = 0; i < 32; ++i) {
      int p = i * 512 + j;
      float a = fmaxf(adjpre4[p] + adjpre4[16384 + p] + adjpre4[32768 + p] +
                      adjpre4[49152 + p] + ab, 0.f);
      msg += a * ((const f32x4*)hn_in_f)[i * 256 + t];
    }
  }
  const int r = isH ? row : row - 32;
  const float* X = (isH ? hn_in_f : node_in_f) + (size_t)r * 1024;
  const float* g = isH ? lnh_g : lno_g;
  const float* bb = isH ? lnh_b : lno_b;
  float* Xo = (isH ? hn_out_f : node_out_f) + (size_t)r * 1024;
  __bf16* Xb = (isH ? hn_bb : node_bb) + (size_t)r * 1024;

  f32x4 x = ((const f32x4*)X)[t];
  f32x4 y;
  #pragma unroll
  for (int e = 0; e < 4; ++e) y[e] = x[e] * GAMA_F + (1.0f - GAMA_F) * msg[e];
  float s = y[0] + y[1] + y[2] + y[3];
  #pragma unroll
  for (int mm = 32; mm >= 1; mm >>= 1) s += __shfl_xor(s, mm);
  if ((t & 63) == 0) sbuf[t >> 6] = s;
  __syncthreads();
  float mean = (sbuf[0] + sbuf[1] + sbuf[2] + sbuf[3]) * (1.0f / 1024.0f);
  __syncthreads();
  f32x4 d;
  #pragma unroll
  for (int e = 0; e < 4; ++e) d[e] = y[e] - mean;
  float sq = d[0] * d[0] + d[1] * d[1] + d[2] * d[2] + d[3] * d[3];
  #pragma unroll
  for (int mm = 32; mm >= 1; mm >>= 1) sq += __shfl_xor(sq, mm);
  if ((t & 63) == 0) sbuf[t >> 6] = sq;
  __syncthreads();
  float var = (sbuf[0] + sbuf[1] + sbuf[2] + sbuf[3]) * (1.0f / 1024.0f);
  float inv = rsqrtf(var + LNEPS);
  f32x4 gg = ((const f32x4*)g)[t];
  f32x4 bv = ((const f32x4*)bb)[t];
  f32x4 o;
  bf16x4 ob;
  #pragma unroll
  for (int e = 0; e < 4; ++e) { o[e] = d[e] * inv * gg[e] + bv[e]; ob[e] = (__bf16)o[e]; }
  ((f32x4*)Xo)[t] = o;
  *(bf16x4*)(Xb + t * 4) = ob;
}

// ---------------- gather ----------------
__global__ void gather_k(const float* __restrict__ hn, const float* __restrict__ node,
                         const float* __restrict__ adjpre4, const float* __restrict__ adjb,
                         float* __restrict__ out) {
  int p = blockIdx.x, t = threadIdx.x;
  int i = p >> 9, j = p & 511;
  if (i == j) return;
  int m = p - (p + 512) / 513;
  float* out0 = out;
  float* out1 = out + (size_t)16352 * 1024;
  float* out2 = out1 + (size_t)16352 * 1024;
  ((f32x4*)out0)[(size_t)m * 256 + t] = ((const f32x4*)hn)[i * 256 + t];
  ((f32x4*)out1)[(size_t)m * 256 + t] = ((const f32x4*)node)[j * 256 + t];
  if (t == 0) {
    out2[m] = fmaxf(adjpre4[p] + adjpre4[16384 + p] + adjpre4[32768 + p] +
                    adjpre4[49152 + p] + adjb[0], 0.f);
    out2[16352 + m] = (float)i;
    out2[2 * 16352 + m] = (float)j;
  }
}

// ---------------- host ----------------
extern "C" void kernel_launch(void* const* d_in, const int* in_sizes, int n_in,
                              void* d_out, int out_size, void* d_ws, size_t ws_size,
                              hipStream_t stream) {
  const float* node_in = (const float*)d_in[1];
  const float* coords  = (const float*)d_in[2];
  const void*  imh     = d_in[3];
  const void*  imw     = d_in[4];
  const float* sp_w1 = (const float*)d_in[5];
  const float* sp_b1 = (const float*)d_in[6];
  const float* sp_w2 = (const float*)d_in[7];
  const float* sp_b2 = (const float*)d_in[8];
  const float* sp_w3 = (const float*)d_in[9];
  const float* sp_b3 = (const float*)d_in[10];
  const float* att_w1 = (const float*)d_in[11];
  const float* att_b1 = (const float*)d_in[12];
  const float* att_w2 = (const float*)d_in[13];
  const float* att_b2 = (const float*)d_in[14];
  const float* att_w3 = (const float*)d_in[15];
  const float* att_b3 = (const float*)d_in[16];
  const float* adj_w  = (const float*)d_in[17];
  const float* adj_b  = (const float*)d_in[18];
  const float* lnh_g  = (const float*)d_in[19];
  const float* lnh_b  = (const float*)d_in[20];
  const float* lno_g  = (const float*)d_in[21];
  const float* lno_b  = (const float*)d_in[22];

  char* w = (char*)d_ws;
  size_t off = 0;
  auto alloc = [&](size_t bytes) -> char* {
    char* p = w + off;
    off += (bytes + 255) & ~(size_t)255;
    return p;
  };
  __bf16* W1at  = (__bf16*)alloc((size_t)1024 * 1024 * 2);
  __bf16* W1bt  = (__bf16*)alloc((size_t)1024 * 1024 * 2);
  __bf16* W2t   = (__bf16*)alloc((size_t)1024 * 1024 * 2);
  __bf16* W3t   = (__bf16*)alloc((size_t)1024 * 1024 * 2);
  __bf16* SpW1t = (__bf16*)alloc(128 * 64 * 2);
  __bf16* SpW2t = (__bf16*)alloc(256 * 128 * 2);
  __bf16* SpW3t = (__bf16*)alloc(1024 * 256 * 2);
  float*  b3s   = (float*)alloc(1024 * 4);
  __bf16* f36   = (__bf16*)alloc((size_t)16384 * 64 * 2);
  __bf16* sp2   = (__bf16*)alloc((size_t)16384 * 256 * 2);
  __bf16* spb   = (__bf16*)alloc((size_t)16384 * 1024 * 2);
  __bf16* u2    = (__bf16*)alloc((size_t)16384 * 1024 * 2);
  float*  H1    = (float*)alloc((size_t)32 * 1024 * 4);
  float*  N1    = (float*)alloc((size_t)512 * 1024 * 4);
  float*  adjpre4 = (float*)alloc((size_t)4 * 16384 * 4);
  float*  node_f0 = (float*)alloc((size_t)512 * 1024 * 4);
  float*  node_f1 = (float*)alloc((size_t)512 * 1024 * 4);
  float*  hn_f0   = (float*)alloc((size_t)32 * 1024 * 4);
  float*  hn_f1   = (float*)alloc((size_t)32 * 1024 * 4);
  __bf16* node_b  = (__bf16*)alloc((size_t)512 * 1024 * 2);
  __bf16* hn_b    = (__bf16*)alloc((size_t)32 * 1024 * 2);
  if (off > ws_size) return;  // fail loud rather than corrupt

  prep_mega<<<3072, 256, 0, stream>>>(att_w1, att_w2, att_w3, sp_w3, sp_w1, sp_w2, att_b3,
                                      node_in, coords, imh, imw,
                                      W1at, W1bt, W2t, W3t, SpW3t, SpW1t, SpW2t, b3s,
                                      node_f0, node_b, hn_f0, hn_b, f36);
  mlp_head<<<128, 256, 0, stream>>>(f36, SpW1t, SpW2t, sp_b1, sp_b2, sp2);
  gemm_bt<0><<<dim3(128, 8), 256, 0, stream>>>(sp2, SpW3t, sp_b3, spb, 16384, 1024, 256);
  gemm_bt<1><<<dim3(128, 8), 256, 0, stream>>>(spb, W2t, att_b2, u2, 16384, 1024, 1024);

  // iter 1: read f0 -> write f1
  gemm_u1<<<dim3(17, 8), 256, 0, stream>>>(hn_b, node_b, W1at, W1bt, att_b1, H1, N1);
  adj_fused<<<dim3(128, 4), 256, 0, stream>>>(u2, H1, N1, W3t, b3s, adj_w, adjpre4);
  msgln<<<544, 256, 0, stream>>>(adjpre4, adj_b, node_f0, hn_f0,
                                 lno_g, lno_b, lnh_g, lnh_b,
                                 node_f1, hn_f1, node_b, hn_b);
  // iter 2: read f1 -> write f0
  gemm_u1<<<dim3(17, 8), 256, 0, stream>>>(hn_b, node_b, W1at, W1bt, att_b1, H1, N1);
  adj_fused<<<dim3(128, 4), 256, 0, stream>>>(u2, H1, N1, W3t, b3s, adj_w, adjpre4);
  msgln<<<544, 256, 0, stream>>>(adjpre4, adj_b, node_f1, hn_f1,
                                 lno_g, lno_b, lnh_g, lnh_b,
                                 node_f0, hn_f0, node_b, hn_b);

  gather_k<<<16384, 256, 0, stream>>>(hn_f0, node_f0, adjpre4, adj_b, (float*)d_out);
}

// Round 4
// 547.574 us; speedup vs baseline: 1.0924x; 1.0924x over previous
//
#include <hip/hip_runtime.h>
#include <hip/hip_bf16.h>

// GCN_55602646614506 — round 4.
// r3 post-mortem: adj_fused was latency-bound (MfmaUtil 11%, occ 22%, HBM 3%) — the
// in-GEMM A-build serialized VGPR global loads against staging at 2 blocks/CU, x4
// redundant. Fix: materialize hdn (64MB round trip ~10us) from a fused u1hdn kernel
// (H1+N1 in LDS, never global), and run the adjacency GEMM as a pure m97-structure
// GEMM (gload_lds, 4 blocks/CU) with plane-partial epilogue (no atomics).

typedef __attribute__((ext_vector_type(4))) float  f32x4;
typedef __attribute__((ext_vector_type(8))) __bf16 bf16x8;
typedef __attribute__((ext_vector_type(4))) __bf16 bf16x4;

#define FEPS 1e-10f
#define LNEPS 1e-5f
#define GAMA_F 0.9f

__device__ __forceinline__ void gload16(const void* g, void* l) {
  __builtin_amdgcn_global_load_lds(
      (const __attribute__((address_space(1))) void*)g,
      (__attribute__((address_space(3))) void*)l, 16, 0, 0);
}

__device__ __forceinline__ float read_dim(const void* p) {
  int iv = *(const int*)p;
  if (iv > 0 && iv < (1 << 20)) return (float)iv;
  return *(const float*)p;
}

// ---------------- prep_mega: weight transposes + small prep + init + spatial ----------------
__global__ void prep_mega(const float* __restrict__ w1, const float* __restrict__ w2,
                          const float* __restrict__ w3, const float* __restrict__ spw3,
                          const float* __restrict__ spw1, const float* __restrict__ spw2,
                          const float* __restrict__ b3,
                          const float* __restrict__ node_in,
                          const float* __restrict__ coords,
                          const void* __restrict__ imh, const void* __restrict__ imw,
                          __bf16* __restrict__ W1at, __bf16* __restrict__ W1bt,
                          __bf16* __restrict__ W2t, __bf16* __restrict__ W3t,
                          __bf16* __restrict__ SpW3t,
                          __bf16* __restrict__ SpW1t, __bf16* __restrict__ SpW2t,
                          float* __restrict__ b3s,
                          float* __restrict__ node_f, __bf16* __restrict__ node_b,
                          float* __restrict__ hn_f, __bf16* __restrict__ hn_b,
                          __bf16* __restrict__ f36) {
  __shared__ float tile[64][65];
  const int b = blockIdx.x, t = threadIdx.x;
  const int tc = t & 63, tr = t >> 6;
  if (b < 256) {
    const int c = b >> 4, d0 = (b & 15) << 6;
    #pragma unroll
    for (int pass = 0; pass < 2; ++pass) {
      const float* src = w1 + (size_t)c * 131072 + (size_t)(d0 + pass * 1024) * 64;
      __bf16* dst = pass ? W1bt : W1at;
      if (pass) __syncthreads();
      #pragma unroll
      for (int q = 0; q < 16; ++q) {
        int dd = q * 4 + tr;
        tile[dd][tc] = src[dd * 64 + tc];
      }
      __syncthreads();
      #pragma unroll
      for (int q = 0; q < 16; ++q) {
        int kk = q * 4 + tr;
        dst[(size_t)(c * 64 + kk) * 1024 + d0 + tc] = (__bf16)tile[tc][kk];
      }
    }
  } else if (b < 512) {
    const int bb = b - 256, c = bb >> 4, s0 = (bb & 15) << 6;
    const float* src = w2 + (size_t)c * 65536 + (size_t)s0 * 64;
    #pragma unroll
    for (int q = 0; q < 16; ++q) {
      int ss = q * 4 + tr;
      tile[ss][tc] = src[ss * 64 + tc];
    }
    __syncthreads();
    #pragma unroll
    for (int q = 0; q < 16; ++q) {
      int kk = q * 4 + tr;
      W2t[(size_t)(c * 64 + kk) * 1024 + s0 + tc] = (__bf16)tile[tc][kk];
    }
  } else if (b < 768) {
    const int bb = b - 512, c = bb >> 4, o0 = (bb & 15) << 6;
    const float* src = w3 + (size_t)c * 65536;
    #pragma unroll
    for (int q = 0; q < 16; ++q) {
      int kk = q * 4 + tr;
      tile[kk][tc] = src[kk * 1024 + o0 + tc];
    }
    __syncthreads();
    #pragma unroll
    for (int q = 0; q < 16; ++q) {
      int oo = q * 4 + tr;
      W3t[(size_t)(o0 + oo) * 1024 + c * 64 + tc] = (__bf16)tile[tc][oo];
    }
  } else if (b < 832) {
    const int bb = b - 768, o0 = (bb >> 2) << 6, k0 = (bb & 3) << 6;
    #pragma unroll
    for (int q = 0; q < 16; ++q) {
      int kk = q * 4 + tr;
      tile[kk][tc] = spw3[(size_t)(k0 + kk) * 1024 + o0 + tc];
    }
    __syncthreads();
    #pragma unroll
    for (int q = 0; q < 16; ++q) {
      int oo = q * 4 + tr;
      SpW3t[(size_t)(o0 + oo) * 256 + k0 + tc] = (__bf16)tile[tc][oo];
    }
  } else if (b < 960) {
    int gid = (b - 832) * 256 + t;
    if (gid < 8192) {
      int n = gid >> 6, k = gid & 63;
      SpW1t[gid] = (k < 36) ? (__bf16)spw1[k * 128 + n] : (__bf16)0.f;
    }
    {
      int n = gid >> 7, k = gid & 127;
      SpW2t[gid] = (__bf16)spw2[k * 256 + n];
    }
    if (gid < 1024) {
      float s = 0.f;
      for (int cc = 0; cc < 16; ++cc) s += b3[cc * 1024 + gid];
      b3s[gid] = s;
    }
  } else if (b < 3008) {
    int gid = (b - 960) * 256 + t;
    float v = node_in[gid];
    node_f[gid] = v;
    node_b[gid] = (__bf16)v;
    if (gid < 32 * 1024) { hn_f[gid] = v; hn_b[gid] = (__bf16)v; }
  } else {
    int p = (b - 3008) * 256 + t;
    int i = p >> 9, j = p & 511;
    float H = read_dim(imh), W = read_dim(imw);
    f32x4 b1 = ((const f32x4*)coords)[i];
    f32x4 b2 = ((const f32x4*)coords)[j];
    float c1x = (b1[0] + b1[2]) * 0.5f, c1y = (b1[1] + b1[3]) * 0.5f;
    float c2x = (b2[0] + b2[2]) * 0.5f, c2y = (b2[1] + b2[3]) * 0.5f;
    float b1w = b1[2] - b1[0], b1h = b1[3] - b1[1];
    float b2w = b2[2] - b2[0], b2h = b2[3] - b2[1];
    float dx = fabsf(c2x - c1x) / (b1w + FEPS);
    float dy = fabsf(c2y - c1y) / (b1h + FEPS);
    float ltx = fmaxf(b1[0], b2[0]), lty = fmaxf(b1[1], b2[1]);
    float rbx = fminf(b1[2], b2[2]), rby = fminf(b1[3], b2[3]);
    float inter = fmaxf(rbx - ltx, 0.f) * fmaxf(rby - lty, 0.f);
    float a1 = b1w * b1h, a2 = b2w * b2h;
    float iou = inter / (a1 + a2 - inter);
    float f[18];
    f[0] = c1x / W;  f[1] = c1y / H;  f[2] = c2x / W;  f[3] = c2y / H;
    f[4] = b1w / W;  f[5] = b1h / H;  f[6] = b2w / W;  f[7] = b2h / H;
    f[8] = a1 / (H * W); f[9] = a2 / (H * W); f[10] = a2 / (a1 + FEPS);
    f[11] = b1w / (b1h + FEPS); f[12] = b2w / (b2h + FEPS); f[13] = iou;
    f[14] = (c2x > c1x) ? dx : 0.f; f[15] = (c2x < c1x) ? dx : 0.f;
    f[16] = (c2y > c1y) ? dy : 0.f; f[17] = (c2y < c1y) ? dy : 0.f;
    __bf16 o[64];
    #pragma unroll
    for (int q = 0; q < 18; ++q) { o[q] = (__bf16)f[q]; o[18 + q] = (__bf16)logf(f[q] + FEPS); }
    #pragma unroll
    for (int q = 36; q < 64; ++q) o[q] = (__bf16)0.f;
    bf16x8* dst = (bf16x8*)(f36 + (size_t)p * 64);
    #pragma unroll
    for (int q = 0; q < 8; ++q) dst[q] = *(bf16x8*)&o[q * 8];
  }
}

// ---------------- mlp_head: sp1 + sp2 fused ----------------
__global__ __launch_bounds__(256)
void mlp_head(const __bf16* __restrict__ f36, const __bf16* __restrict__ SpW1t,
              const __bf16* __restrict__ SpW2t, const float* __restrict__ b1,
              const float* __restrict__ b2, __bf16* __restrict__ sp2out) {
  __shared__ __align__(16) __bf16 Af[128 * 64];
  __shared__ __align__(16) __bf16 W1s[128 * 64];
  __shared__ __align__(16) __bf16 S1[128 * 128];
  __shared__ __align__(16) __bf16 W2s[256 * 128];
  const int t = threadIdx.x;
  const int lane = t & 63, wv = t >> 6;
  const int wr = wv >> 1, wc = wv & 1;
  const int lr = lane & 15, lg = lane >> 4;
  const int m0 = blockIdx.x * 128;

  #pragma unroll
  for (int cc = 0; cc < 4; ++cc)
    gload16(f36 + (size_t)m0 * 64 + (wv * 4 + cc) * 512 + lane * 8, &Af[(wv * 4 + cc) * 512 + lane * 8]);
  #pragma unroll
  for (int cc = 0; cc < 4; ++cc)
    gload16(SpW1t + (wv * 4 + cc) * 512 + lane * 8, &W1s[(wv * 4 + cc) * 512 + lane * 8]);
  #pragma unroll
  for (int cc = 0; cc < 16; ++cc)
    gload16(SpW2t + (wv * 16 + cc) * 512 + lane * 8, &W2s[(wv * 16 + cc) * 512 + lane * 8]);
  __syncthreads();

  {
    f32x4 acc[4][4] = {};
    #pragma unroll
    for (int ks = 0; ks < 2; ++ks) {
      bf16x8 af[4], bf[4];
      #pragma unroll
      for (int mi = 0; mi < 4; ++mi)
        af[mi] = *(const bf16x8*)&Af[(wr * 64 + mi * 16 + lr) * 64 + ks * 32 + lg * 8];
      #pragma unroll
      for (int ni = 0; ni < 4; ++ni)
        bf[ni] = *(const bf16x8*)&W1s[(wc * 64 + ni * 16 + lr) * 64 + ks * 32 + lg * 8];
      #pragma unroll
      for (int mi = 0; mi < 4; ++mi)
        #pragma unroll
        for (int ni = 0; ni < 4; ++ni)
          acc[mi][ni] = __builtin_amdgcn_mfma_f32_16x16x32_bf16(af[mi], bf[ni], acc[mi][ni], 0, 0, 0);
    }
    __syncthreads();
    #pragma unroll
    for (int mi = 0; mi < 4; ++mi)
      #pragma unroll
      for (int r = 0; r < 4; ++r) {
        int R = wr * 64 + mi * 16 + lg * 4 + r;
        #pragma unroll
        for (int ni = 0; ni < 4; ++ni) {
          int Cc = wc * 64 + ni * 16 + lr;
          S1[R * 128 + Cc] = (__bf16)fmaxf(acc[mi][ni][r] + b1[Cc], 0.f);
        }
      }
  }
  __syncthreads();

  {
    f32x4 acc[4][8] = {};
    #pragma unroll
    for (int ks = 0; ks < 4; ++ks) {
      bf16x8 af[4];
      #pragma unroll
      for (int mi = 0; mi < 4; ++mi)
        af[mi] = *(const bf16x8*)&S1[(wr * 64 + mi * 16 + lr) * 128 + ks * 32 + lg * 8];
      #pragma unroll
      for (int ni = 0; ni < 8; ++ni) {
        bf16x8 bf = *(const bf16x8*)&W2s[(wc * 128 + ni * 16 + lr) * 128 + ks * 32 + lg * 8];
        #pragma unroll
        for (int mi = 0; mi < 4; ++mi)
          acc[mi][ni] = __builtin_amdgcn_mfma_f32_16x16x32_bf16(af[mi], bf, acc[mi][ni], 0, 0, 0);
      }
    }
    #pragma unroll
    for (int mi = 0; mi < 4; ++mi)
      #pragma unroll
      for (int r = 0; r < 4; ++r) {
        int R = m0 + wr * 64 + mi * 16 + lg * 4 + r;
        #pragma unroll
        for (int ni = 0; ni < 8; ++ni) {
          int Cc = wc * 128 + ni * 16 + lr;
          sp2out[(size_t)R * 256 + Cc] = (__bf16)fmaxf(acc[mi][ni][r] + b2[Cc], 0.f);
        }
      }
  }
}

// ---------------- generic MFMA GEMM (m97 structure) ----------------
template <int EPI>  // 0 relu+bias->bf16; 1 bias->bf16
__global__ __launch_bounds__(256)
void gemm_bt(const __bf16* __restrict__ A, const __bf16* __restrict__ Bt,
             const float* __restrict__ bias, void* __restrict__ C,
             int M, int N, int K) {
  __shared__ __align__(16) __bf16 As[128 * 64];
  __shared__ __align__(16) __bf16 Bs[128 * 64];
  const int t = threadIdx.x;
  const int lane = t & 63, wv = t >> 6;
  const int wr = wv >> 1, wc = wv & 1;
  const int lr = lane & 15, lg = lane >> 4;
  const int lrow = lane >> 3, lcol = (lane & 7) << 3;
  const int m0 = blockIdx.x * 128, n0 = blockIdx.y * 128;

  f32x4 acc[4][4] = {};
  const int nkt = K >> 6;
  for (int kt = 0; kt < nkt; ++kt) {
    const int k0 = kt << 6;
    #pragma unroll
    for (int it = 0; it < 4; ++it) {
      const int rbase = wv * 32 + it * 8;
      gload16(A + (size_t)(m0 + rbase + lrow) * K + k0 + lcol, &As[rbase * 64]);
      gload16(Bt + (size_t)(n0 + rbase + lrow) * K + k0 + lcol, &Bs[rbase * 64]);
    }
    __syncthreads();
    #pragma unroll
    for (int ks = 0; ks < 2; ++ks) {
      bf16x8 af[4], bfr[4];
      #pragma unroll
      for (int mi = 0; mi < 4; ++mi)
        af[mi] = *(const bf16x8*)&As[(wr * 64 + mi * 16 + lr) * 64 + ks * 32 + lg * 8];
      #pragma unroll
      for (int ni = 0; ni < 4; ++ni)
        bfr[ni] = *(const bf16x8*)&Bs[(wc * 64 + ni * 16 + lr) * 64 + ks * 32 + lg * 8];
      #pragma unroll
      for (int mi = 0; mi < 4; ++mi)
        #pragma unroll
        for (int ni = 0; ni < 4; ++ni)
          acc[mi][ni] = __builtin_amdgcn_mfma_f32_16x16x32_bf16(af[mi], bfr[ni], acc[mi][ni], 0, 0, 0);
    }
    __syncthreads();
  }
  #pragma unroll
  for (int mi = 0; mi < 4; ++mi)
    #pragma unroll
    for (int r = 0; r < 4; ++r) {
      int R = m0 + wr * 64 + mi * 16 + lg * 4 + r;
      #pragma unroll
      for (int ni = 0; ni < 4; ++ni) {
        int Cc = n0 + wc * 64 + ni * 16 + lr;
        float v = acc[mi][ni][r] + bias[Cc];
        if constexpr (EPI == 0) v = fmaxf(v, 0.f);
        ((__bf16*)C)[(size_t)R * N + Cc] = (__bf16)v;
      }
    }
}

// ---------------- u1hdn: H1(32x128, redundant) + N1(32x128) in LDS -> hdn write ----------------
// grid (16, 8): x = node-row block (32 rows), y = column block (128 cols)
__global__ __launch_bounds__(256)
void u1hdn(const __bf16* __restrict__ hn_b, const __bf16* __restrict__ node_b,
           const __bf16* __restrict__ W1at, const __bf16* __restrict__ W1bt,
           const float* __restrict__ b1, const __bf16* __restrict__ u2,
           __bf16* __restrict__ hdn) {
  __shared__ __align__(16) __bf16 AsH[32 * 64];
  __shared__ __align__(16) __bf16 AsN[32 * 64];
  __shared__ __align__(16) __bf16 BsH[128 * 64];   // overlaid by H1s (32x128 f32) post-GEMM
  __shared__ __align__(16) __bf16 BsN[128 * 64];   // overlaid by N1s
  const int t = threadIdx.x;
  const int lane = t & 63, wv = t >> 6;
  const int lr = lane & 15, lg = lane >> 4;
  const int lrow = lane >> 3, lcol = (lane & 7) << 3;
  const int j0 = blockIdx.x * 32;
  const int n0 = blockIdx.y * 128;
  const bool isH = wv < 2;
  const int r0 = (wv & 1) * 16;

  f32x4 acc[8] = {};
  for (int kt = 0; kt < 16; ++kt) {
    const int k0 = kt << 6;
    gload16(hn_b + (size_t)(wv * 8 + lrow) * 1024 + k0 + lcol, &AsH[(wv * 8) * 64]);
    gload16(node_b + (size_t)(j0 + wv * 8 + lrow) * 1024 + k0 + lcol, &AsN[(wv * 8) * 64]);
    #pragma unroll
    for (int it = 0; it < 4; ++it) {
      const int rbase = wv * 32 + it * 8;
      gload16(W1at + (size_t)(n0 + rbase + lrow) * 1024 + k0 + lcol, &BsH[rbase * 64]);
      gload16(W1bt + (size_t)(n0 + rbase + lrow) * 1024 + k0 + lcol, &BsN[rbase * 64]);
    }
    __syncthreads();
    const __bf16* Asrc = isH ? AsH : AsN;
    const __bf16* Bsrc = isH ? BsH : BsN;
    #pragma unroll
    for (int ks = 0; ks < 2; ++ks) {
      bf16x8 af = *(const bf16x8*)&Asrc[(r0 + lr) * 64 + ks * 32 + lg * 8];
      #pragma unroll
      for (int ni = 0; ni < 8; ++ni) {
        bf16x8 bfr = *(const bf16x8*)&Bsrc[(ni * 16 + lr) * 64 + ks * 32 + lg * 8];
        acc[ni] = __builtin_amdgcn_mfma_f32_16x16x32_bf16(af, bfr, acc[ni], 0, 0, 0);
      }
    }
    __syncthreads();
  }

  // write results into LDS overlays (H1 gets bias)
  float* H1s = (float*)BsH;
  float* N1s = (float*)BsN;
  #pragma unroll
  for (int ni = 0; ni < 8; ++ni)
    #pragma unroll
    for (int r = 0; r < 4; ++r) {
      int row = r0 + lg * 4 + r;
      int col = ni * 16 + lr;
      float v = acc[ni][r];
      if (isH) H1s[row * 128 + col] = v + b1[n0 + col];
      else     N1s[row * 128 + col] = v;
    }
  __syncthreads();

  // hdn epilogue: 1024 p-rows x 128 cols
  const int rsub = t >> 4, csub = (t & 15) * 8;
  for (int pass = 0; pass < 64; ++pass) {
    int rp = pass * 16 + rsub;
    int i = rp >> 5, jl = rp & 31;
    size_t p = (size_t)i * 512 + j0 + jl;
    bf16x8 u = *(const bf16x8*)(u2 + p * 1024 + n0 + csub);
    const float* hp = &H1s[i * 128 + csub];
    const float* np = &N1s[jl * 128 + csub];
    bf16x8 o;
    #pragma unroll
    for (int e = 0; e < 8; ++e)
      o[e] = (__bf16)fmaxf((hp[e] + np[e]) * (float)u[e], 0.f);
    *(bf16x8*)(hdn + p * 1024 + n0 + csub) = o;
  }
}

// ---------------- gemm_adj: m97 GEMM + adjacency-dot epilogue into planes ----------------
// grid (128, 8): h = blockIdx.y plane, cols h*128..h*128+128
__global__ __launch_bounds__(256)
void gemm_adj(const __bf16* __restrict__ hdn, const __bf16* __restrict__ W3t,
              const float* __restrict__ b3s, const float* __restrict__ adjw,
              float* __restrict__ adjpre8) {
  __shared__ __align__(16) __bf16 As[128 * 64];
  __shared__ __align__(16) __bf16 Bs[128 * 64];
  __shared__ float redbuf[2][128];
  const int t = threadIdx.x;
  const int lane = t & 63, wv = t >> 6;
  const int wr = wv >> 1, wc = wv & 1;
  const int lr = lane & 15, lg = lane >> 4;
  const int lrow = lane >> 3, lcol = (lane & 7) << 3;
  const int m0 = blockIdx.x * 128;
  const int h = blockIdx.y, c0 = h * 128;

  f32x4 acc[4][4] = {};
  for (int kt = 0; kt < 16; ++kt) {
    const int k0 = kt << 6;
    #pragma unroll
    for (int it = 0; it < 4; ++it) {
      const int rbase = wv * 32 + it * 8;
      gload16(hdn + (size_t)(m0 + rbase + lrow) * 1024 + k0 + lcol, &As[rbase * 64]);
      gload16(W3t + (size_t)(c0 + rbase + lrow) * 1024 + k0 + lcol, &Bs[rbase * 64]);
    }
    __syncthreads();
    #pragma unroll
    for (int ks = 0; ks < 2; ++ks) {
      bf16x8 af[4], bfr[4];
      #pragma unroll
      for (int mi = 0; mi < 4; ++mi)
        af[mi] = *(const bf16x8*)&As[(wr * 64 + mi * 16 + lr) * 64 + ks * 32 + lg * 8];
      #pragma unroll
      for (int ni = 0; ni < 4; ++ni)
        bfr[ni] = *(const bf16x8*)&Bs[(wc * 64 + ni * 16 + lr) * 64 + ks * 32 + lg * 8];
      #pragma unroll
      for (int mi = 0; mi < 4; ++mi)
        #pragma unroll
        for (int ni = 0; ni < 4; ++ni)
          acc[mi][ni] = __builtin_amdgcn_mfma_f32_16x16x32_bf16(af[mi], bfr[ni], acc[mi][ni], 0, 0, 0);
    }
    __syncthreads();
  }

  float b3v[4], awv[4];
  #pragma unroll
  for (int ni = 0; ni < 4; ++ni) {
    int Cc = c0 + wc * 64 + ni * 16 + lr;
    b3v[ni] = b3s[Cc];
    awv[ni] = adjw[Cc];
  }
  #pragma unroll
  for (int mi = 0; mi < 4; ++mi)
    #pragma unroll
    for (int r = 0; r < 4; ++r) {
      float s = 0.f;
      #pragma unroll
      for (int ni = 0; ni < 4; ++ni)
        s += fmaxf(acc[mi][ni][r] + b3v[ni], 0.f) * awv[ni];
      s += __shfl_xor(s, 1);
      s += __shfl_xor(s, 2);
      s += __shfl_xor(s, 4);
      s += __shfl_xor(s, 8);
      if (lr == 0)
        redbuf[wc][wr * 64 + mi * 16 + lg * 4 + r] = s;
    }
  __syncthreads();
  if (t < 128)
    adjpre8[(size_t)h * 16384 + m0 + t] = redbuf[0][t] + redbuf[1][t];
}

// ---------------- msg + LN merged (ping-pong, 8 planes) ----------------
__global__ void msgln(const float* __restrict__ adjpre8, const float* __restrict__ adjb,
                      const float* __restrict__ node_in_f, const float* __restrict__ hn_in_f,
                      const float* __restrict__ lno_g, const float* __restrict__ lno_b,
                      const float* __restrict__ lnh_g, const float* __restrict__ lnh_b,
                      float* __restrict__ node_out_f, float* __restrict__ hn_out_f,
                      __bf16* __restrict__ node_bb, __bf16* __restrict__ hn_bb) {
  __shared__ float adjrow[512];
  __shared__ float sbuf[4];
  const int row = blockIdx.x, t = threadIdx.x;
  const float ab = adjb[0];
  const bool isH = row < 32;
  f32x4 msg = {0.f, 0.f, 0.f, 0.f};
  if (isH) {
    const int i = row;
    float s0 = 0.f, s1 = 0.f;
    #pragma unroll
    for (int h = 0; h < 8; ++h) {
      s0 += adjpre8[(size_t)h * 16384 + i * 512 + t];
      s1 += adjpre8[(size_t)h * 16384 + i * 512 + 256 + t];
    }
    adjrow[t] = fmaxf(s0 + ab, 0.f);
    adjrow[256 + t] = fmaxf(s1 + ab, 0.f);
    __syncthreads();
    for (int j = 0; j < 512; ++j)
      msg += adjrow[j] * ((const f32x4*)node_in_f)[j * 256 + t];
  } else {
    const int j = row - 32;
    int i = t >> 3, hh = t & 7;
    float v = adjpre8[(size_t)hh * 16384 + i * 512 + j];
    v += __shfl_xor(v, 1);
    v += __shfl_xor(v, 2);
    v += __shfl_xor(v, 4);
    if (hh == 0) adjrow[i] = fmaxf(v + ab, 0.f);
    __syncthreads();
    for (int i2 = 0; i2 < 32; ++i2)
      msg += adjrow[i2] * ((const f32x4*)hn_in_f)[i2 * 256 + t];
  }
  const int r = isH ? row : row - 32;
  const float* X = (isH ? hn_in_f : node_in_f) + (size_t)r * 1024;
  const float* g = isH ? lnh_g : lno_g;
  const float* bb = isH ? lnh_b : lno_b;
  float* Xo = (isH ? hn_out_f : node_out_f) + (size_t)r * 1024;
  __bf16* Xb = (isH ? hn_bb : node_bb) + (size_t)r * 1024;

  f32x4 x = ((const f32x4*)X)[t];
  f32x4 y;
  #pragma unroll
  for (int e = 0; e < 4; ++e) y[e] = x[e] * GAMA_F + (1.0f - GAMA_F) * msg[e];
  float s = y[0] + y[1] + y[2] + y[3];
  #pragma unroll
  for (int mm = 32; mm >= 1; mm >>= 1) s += __shfl_xor(s, mm);
  if ((t & 63) == 0) sbuf[t >> 6] = s;
  __syncthreads();
  float mean = (sbuf[0] + sbuf[1] + sbuf[2] + sbuf[3]) * (1.0f / 1024.0f);
  __syncthreads();
  f32x4 d;
  #pragma unroll
  for (int e = 0; e < 4; ++e) d[e] = y[e] - mean;
  float sq = d[0] * d[0] + d[1] * d[1] + d[2] * d[2] + d[3] * d[3];
  #pragma unroll
  for (int mm = 32; mm >= 1; mm >>= 1) sq += __shfl_xor(sq, mm);
  if ((t & 63) == 0) sbuf[t >> 6] = sq;
  __syncthreads();
  float var = (sbuf[0] + sbuf[1] + sbuf[2] + sbuf[3]) * (1.0f / 1024.0f);
  float inv = rsqrtf(var + LNEPS);
  f32x4 gg = ((const f32x4*)g)[t];
  f32x4 bv = ((const f32x4*)bb)[t];
  f32x4 o;
  bf16x4 ob;
  #pragma unroll
  for (int e = 0; e < 4; ++e) { o[e] = d[e] * inv * gg[e] + bv[e]; ob[e] = (__bf16)o[e]; }
  ((f32x4*)Xo)[t] = o;
  *(bf16x4*)(Xb + t * 4) = ob;
}

// ---------------- gather ----------------
__global__ void gather_k(const float* __restrict__ hn, const float* __restrict__ node,
                         const float* __restrict__ adjpre8, const float* __restrict__ adjb,
                         float* __restrict__ out) {
  int p = blockIdx.x, t = threadIdx.x;
  int i = p >> 9, j = p & 511;
  if (i == j) return;
  int m = p - (p + 512) / 513;
  float* out0 = out;
  float* out1 = out + (size_t)16352 * 1024;
  float* out2 = out1 + (size_t)16352 * 1024;
  ((f32x4*)out0)[(size_t)m * 256 + t] = ((const f32x4*)hn)[i * 256 + t];
  ((f32x4*)out1)[(size_t)m * 256 + t] = ((const f32x4*)node)[j * 256 + t];
  if (t == 0) {
    float s = adjb[0];
    #pragma unroll
    for (int h = 0; h < 8; ++h) s += adjpre8[(size_t)h * 16384 + p];
    out2[m] = fmaxf(s, 0.f);
    out2[16352 + m] = (float)i;
    out2[2 * 16352 + m] = (float)j;
  }
}

// ---------------- host ----------------
extern "C" void kernel_launch(void* const* d_in, const int* in_sizes, int n_in,
                              void* d_out, int out_size, void* d_ws, size_t ws_size,
                              hipStream_t stream) {
  const float* node_in = (const float*)d_in[1];
  const float* coords  = (const float*)d_in[2];
  const void*  imh     = d_in[3];
  const void*  imw     = d_in[4];
  const float* sp_w1 = (const float*)d_in[5];
  const float* sp_b1 = (const float*)d_in[6];
  const float* sp_w2 = (const float*)d_in[7];
  const float* sp_b2 = (const float*)d_in[8];
  const float* sp_w3 = (const float*)d_in[9];
  const float* sp_b3 = (const float*)d_in[10];
  const float* att_w1 = (const float*)d_in[11];
  const float* att_b1 = (const float*)d_in[12];
  const float* att_w2 = (const float*)d_in[13];
  const float* att_b2 = (const float*)d_in[14];
  const float* att_w3 = (const float*)d_in[15];
  const float* att_b3 = (const float*)d_in[16];
  const float* adj_w  = (const float*)d_in[17];
  const float* adj_b  = (const float*)d_in[18];
  const float* lnh_g  = (const float*)d_in[19];
  const float* lnh_b  = (const float*)d_in[20];
  const float* lno_g  = (const float*)d_in[21];
  const float* lno_b  = (const float*)d_in[22];

  char* w = (char*)d_ws;
  size_t off = 0;
  auto alloc = [&](size_t bytes) -> char* {
    char* p = w + off;
    off += (bytes + 255) & ~(size_t)255;
    return p;
  };
  __bf16* W1at  = (__bf16*)alloc((size_t)1024 * 1024 * 2);
  __bf16* W1bt  = (__bf16*)alloc((size_t)1024 * 1024 * 2);
  __bf16* W2t   = (__bf16*)alloc((size_t)1024 * 1024 * 2);
  __bf16* W3t   = (__bf16*)alloc((size_t)1024 * 1024 * 2);
  __bf16* SpW1t = (__bf16*)alloc(128 * 64 * 2);
  __bf16* SpW2t = (__bf16*)alloc(256 * 128 * 2);
  __bf16* SpW3t = (__bf16*)alloc(1024 * 256 * 2);
  float*  b3s   = (float*)alloc(1024 * 4);
  __bf16* f36   = (__bf16*)alloc((size_t)16384 * 64 * 2);
  __bf16* sp2   = (__bf16*)alloc((size_t)16384 * 256 * 2);
  __bf16* spb   = (__bf16*)alloc((size_t)16384 * 1024 * 2);  // reused as hdn after u2
  __bf16* u2    = (__bf16*)alloc((size_t)16384 * 1024 * 2);
  float*  adjpre8 = (float*)alloc((size_t)8 * 16384 * 4);
  float*  node_f0 = (float*)alloc((size_t)512 * 1024 * 4);
  float*  node_f1 = (float*)alloc((size_t)512 * 1024 * 4);
  float*  hn_f0   = (float*)alloc((size_t)32 * 1024 * 4);
  float*  hn_f1   = (float*)alloc((size_t)32 * 1024 * 4);
  __bf16* node_b  = (__bf16*)alloc((size_t)512 * 1024 * 2);
  __bf16* hn_b    = (__bf16*)alloc((size_t)32 * 1024 * 2);
  if (off > ws_size) return;  // fail loud rather than corrupt

  prep_mega<<<3072, 256, 0, stream>>>(att_w1, att_w2, att_w3, sp_w3, sp_w1, sp_w2, att_b3,
                                      node_in, coords, imh, imw,
                                      W1at, W1bt, W2t, W3t, SpW3t, SpW1t, SpW2t, b3s,
                                      node_f0, node_b, hn_f0, hn_b, f36);
  mlp_head<<<128, 256, 0, stream>>>(f36, SpW1t, SpW2t, sp_b1, sp_b2, sp2);
  gemm_bt<0><<<dim3(128, 8), 256, 0, stream>>>(sp2, SpW3t, sp_b3, spb, 16384, 1024, 256);
  gemm_bt<1><<<dim3(128, 8), 256, 0, stream>>>(spb, W2t, att_b2, u2, 16384, 1024, 1024);

  __bf16* hdn = spb;  // spb dead after u2
  // iter 1: read f0 -> write f1
  u1hdn<<<dim3(16, 8), 256, 0, stream>>>(hn_b, node_b, W1at, W1bt, att_b1, u2, hdn);
  gemm_adj<<<dim3(128, 8), 256, 0, stream>>>(hdn, W3t, b3s, adj_w, adjpre8);
  msgln<<<544, 256, 0, stream>>>(adjpre8, adj_b, node_f0, hn_f0,
                                 lno_g, lno_b, lnh_g, lnh_b,
                                 node_f1, hn_f1, node_b, hn_b);
  // iter 2: read f1 -> write f0
  u1hdn<<<dim3(16, 8), 256, 0, stream>>>(hn_b, node_b, W1at, W1bt, att_b1, u2, hdn);
  gemm_adj<<<dim3(128, 8), 256, 0, stream>>>(hdn, W3t, b3s, adj_w, adjpre8);
  msgln<<<544, 256, 0, stream>>>(adjpre8, adj_b, node_f1, hn_f1,
                                 lno_g, lno_b, lnh_g, lnh_b,
                                 node_f0, hn_f0, node_b, hn_b);

  gather_k<<<16384, 256, 0, stream>>>(hn_f0, node_f0, adjpre8, adj_b, (float*)d_out);
}

// Round 5
// 501.410 us; speedup vs baseline: 1.1930x; 1.0921x over previous
//
#include <hip/hip_runtime.h>
#include <hip/hip_bf16.h>

// GCN_55602646614506 — round 5.
// r4 post-mortem: u1hdn (128 blocks, half-GPU idle) and mlp_head (128KB LDS -> 1
// block/CU) were latency losers; big GEMMs ~500 TF. Changes: (1) u1hdn un-fused back
// to gemm_u1 + wide build_hdn (r2-proven); (2) mlp_head v2: BM=64, 24KB LDS, W1/W2
// read direct from L2; (3) XCD-grouped 1-D swizzle on spb/u2/adj GEMMs so each XCD's
// A-panels stay L2-resident across their 8 column-block reuses.

typedef __attribute__((ext_vector_type(4))) float  f32x4;
typedef __attribute__((ext_vector_type(8))) __bf16 bf16x8;
typedef __attribute__((ext_vector_type(4))) __bf16 bf16x4;

#define FEPS 1e-10f
#define LNEPS 1e-5f
#define GAMA_F 0.9f

__device__ __forceinline__ void gload16(const void* g, void* l) {
  __builtin_amdgcn_global_load_lds(
      (const __attribute__((address_space(1))) void*)g,
      (__attribute__((address_space(3))) void*)l, 16, 0, 0);
}

__device__ __forceinline__ float read_dim(const void* p) {
  int iv = *(const int*)p;
  if (iv > 0 && iv < (1 << 20)) return (float)iv;
  return *(const float*)p;
}

// ---------------- prep_mega ----------------
__global__ void prep_mega(const float* __restrict__ w1, const float* __restrict__ w2,
                          const float* __restrict__ w3, const float* __restrict__ spw3,
                          const float* __restrict__ spw1, const float* __restrict__ spw2,
                          const float* __restrict__ b3,
                          const float* __restrict__ node_in,
                          const float* __restrict__ coords,
                          const void* __restrict__ imh, const void* __restrict__ imw,
                          __bf16* __restrict__ W1at, __bf16* __restrict__ W1bt,
                          __bf16* __restrict__ W2t, __bf16* __restrict__ W3t,
                          __bf16* __restrict__ SpW3t,
                          __bf16* __restrict__ SpW1t, __bf16* __restrict__ SpW2t,
                          float* __restrict__ b3s,
                          float* __restrict__ node_f, __bf16* __restrict__ node_b,
                          float* __restrict__ hn_f, __bf16* __restrict__ hn_b,
                          __bf16* __restrict__ f36) {
  __shared__ float tile[64][65];
  const int b = blockIdx.x, t = threadIdx.x;
  const int tc = t & 63, tr = t >> 6;
  if (b < 256) {
    const int c = b >> 4, d0 = (b & 15) << 6;
    #pragma unroll
    for (int pass = 0; pass < 2; ++pass) {
      const float* src = w1 + (size_t)c * 131072 + (size_t)(d0 + pass * 1024) * 64;
      __bf16* dst = pass ? W1bt : W1at;
      if (pass) __syncthreads();
      #pragma unroll
      for (int q = 0; q < 16; ++q) {
        int dd = q * 4 + tr;
        tile[dd][tc] = src[dd * 64 + tc];
      }
      __syncthreads();
      #pragma unroll
      for (int q = 0; q < 16; ++q) {
        int kk = q * 4 + tr;
        dst[(size_t)(c * 64 + kk) * 1024 + d0 + tc] = (__bf16)tile[tc][kk];
      }
    }
  } else if (b < 512) {
    const int bb = b - 256, c = bb >> 4, s0 = (bb & 15) << 6;
    const float* src = w2 + (size_t)c * 65536 + (size_t)s0 * 64;
    #pragma unroll
    for (int q = 0; q < 16; ++q) {
      int ss = q * 4 + tr;
      tile[ss][tc] = src[ss * 64 + tc];
    }
    __syncthreads();
    #pragma unroll
    for (int q = 0; q < 16; ++q) {
      int kk = q * 4 + tr;
      W2t[(size_t)(c * 64 + kk) * 1024 + s0 + tc] = (__bf16)tile[tc][kk];
    }
  } else if (b < 768) {
    const int bb = b - 512, c = bb >> 4, o0 = (bb & 15) << 6;
    const float* src = w3 + (size_t)c * 65536;
    #pragma unroll
    for (int q = 0; q < 16; ++q) {
      int kk = q * 4 + tr;
      tile[kk][tc] = src[kk * 1024 + o0 + tc];
    }
    __syncthreads();
    #pragma unroll
    for (int q = 0; q < 16; ++q) {
      int oo = q * 4 + tr;
      W3t[(size_t)(o0 + oo) * 1024 + c * 64 + tc] = (__bf16)tile[tc][oo];
    }
  } else if (b < 832) {
    const int bb = b - 768, o0 = (bb >> 2) << 6, k0 = (bb & 3) << 6;
    #pragma unroll
    for (int q = 0; q < 16; ++q) {
      int kk = q * 4 + tr;
      tile[kk][tc] = spw3[(size_t)(k0 + kk) * 1024 + o0 + tc];
    }
    __syncthreads();
    #pragma unroll
    for (int q = 0; q < 16; ++q) {
      int oo = q * 4 + tr;
      SpW3t[(size_t)(o0 + oo) * 256 + k0 + tc] = (__bf16)tile[tc][oo];
    }
  } else if (b < 960) {
    int gid = (b - 832) * 256 + t;
    if (gid < 8192) {
      int n = gid >> 6, k = gid & 63;
      SpW1t[gid] = (k < 36) ? (__bf16)spw1[k * 128 + n] : (__bf16)0.f;
    }
    {
      int n = gid >> 7, k = gid & 127;
      SpW2t[gid] = (__bf16)spw2[k * 256 + n];
    }
    if (gid < 1024) {
      float s = 0.f;
      for (int cc = 0; cc < 16; ++cc) s += b3[cc * 1024 + gid];
      b3s[gid] = s;
    }
  } else if (b < 3008) {
    int gid = (b - 960) * 256 + t;
    float v = node_in[gid];
    node_f[gid] = v;
    node_b[gid] = (__bf16)v;
    if (gid < 32 * 1024) { hn_f[gid] = v; hn_b[gid] = (__bf16)v; }
  } else {
    int p = (b - 3008) * 256 + t;
    int i = p >> 9, j = p & 511;
    float H = read_dim(imh), W = read_dim(imw);
    f32x4 b1 = ((const f32x4*)coords)[i];
    f32x4 b2 = ((const f32x4*)coords)[j];
    float c1x = (b1[0] + b1[2]) * 0.5f, c1y = (b1[1] + b1[3]) * 0.5f;
    float c2x = (b2[0] + b2[2]) * 0.5f, c2y = (b2[1] + b2[3]) * 0.5f;
    float b1w = b1[2] - b1[0], b1h = b1[3] - b1[1];
    float b2w = b2[2] - b2[0], b2h = b2[3] - b2[1];
    float dx = fabsf(c2x - c1x) / (b1w + FEPS);
    float dy = fabsf(c2y - c1y) / (b1h + FEPS);
    float ltx = fmaxf(b1[0], b2[0]), lty = fmaxf(b1[1], b2[1]);
    float rbx = fminf(b1[2], b2[2]), rby = fminf(b1[3], b2[3]);
    float inter = fmaxf(rbx - ltx, 0.f) * fmaxf(rby - lty, 0.f);
    float a1 = b1w * b1h, a2 = b2w * b2h;
    float iou = inter / (a1 + a2 - inter);
    float f[18];
    f[0] = c1x / W;  f[1] = c1y / H;  f[2] = c2x / W;  f[3] = c2y / H;
    f[4] = b1w / W;  f[5] = b1h / H;  f[6] = b2w / W;  f[7] = b2h / H;
    f[8] = a1 / (H * W); f[9] = a2 / (H * W); f[10] = a2 / (a1 + FEPS);
    f[11] = b1w / (b1h + FEPS); f[12] = b2w / (b2h + FEPS); f[13] = iou;
    f[14] = (c2x > c1x) ? dx : 0.f; f[15] = (c2x < c1x) ? dx : 0.f;
    f[16] = (c2y > c1y) ? dy : 0.f; f[17] = (c2y < c1y) ? dy : 0.f;
    __bf16 o[64];
    #pragma unroll
    for (int q = 0; q < 18; ++q) { o[q] = (__bf16)f[q]; o[18 + q] = (__bf16)logf(f[q] + FEPS); }
    #pragma unroll
    for (int q = 36; q < 64; ++q) o[q] = (__bf16)0.f;
    bf16x8* dst = (bf16x8*)(f36 + (size_t)p * 64);
    #pragma unroll
    for (int q = 0; q < 8; ++q) dst[q] = *(bf16x8*)&o[q * 8];
  }
}

// ---------------- mlp_head v2: BM=64, 24KB LDS, W1/W2 direct from L2 ----------------
// grid 256 x 256 threads
__global__ __launch_bounds__(256)
void mlp_head(const __bf16* __restrict__ f36, const __bf16* __restrict__ SpW1t,
              const __bf16* __restrict__ SpW2t, const float* __restrict__ b1,
              const float* __restrict__ b2, __bf16* __restrict__ sp2out) {
  __shared__ __align__(16) __bf16 Af[64 * 64];    // 8KB
  __shared__ __align__(16) __bf16 S1[64 * 128];   // 16KB
  const int t = threadIdx.x;
  const int lane = t & 63, wv = t >> 6;
  const int wr = wv >> 1, wc = wv & 1;            // 2x2 warp grid
  const int lr = lane & 15, lg = lane >> 4;
  const int m0 = blockIdx.x * 64;

  // stage f36 tile (8KB = 2 rounds of 256x16B)
  gload16(f36 + (size_t)m0 * 64 + t * 16, &Af[t * 16]);
  // second half offset by 4096 elements
  gload16(f36 + (size_t)m0 * 64 + 4096 + t * 8, &Af[4096 + t * 8]);
  __syncthreads();

  // sp1 = relu(f36 @ W1^T + b1): 64x128, K=64. A rows: wr*32+mi*16, cols wc*64+ni*16
  {
    f32x4 acc[2][4] = {};
    #pragma unroll
    for (int ks = 0; ks < 2; ++ks) {
      bf16x8 af[2], bf[4];
      #pragma unroll
      for (int mi = 0; mi < 2; ++mi)
        af[mi] = *(const bf16x8*)&Af[(wr * 32 + mi * 16 + lr) * 64 + ks * 32 + lg * 8];
      #pragma unroll
      for (int ni = 0; ni < 4; ++ni)
        bf[ni] = *(const bf16x8*)(SpW1t + (size_t)(wc * 64 + ni * 16 + lr) * 64 + ks * 32 + lg * 8);
      #pragma unroll
      for (int mi = 0; mi < 2; ++mi)
        #pragma unroll
        for (int ni = 0; ni < 4; ++ni)
          acc[mi][ni] = __builtin_amdgcn_mfma_f32_16x16x32_bf16(af[mi], bf[ni], acc[mi][ni], 0, 0, 0);
    }
    #pragma unroll
    for (int mi = 0; mi < 2; ++mi)
      #pragma unroll
      for (int r = 0; r < 4; ++r) {
        int R = wr * 32 + mi * 16 + lg * 4 + r;
        #pragma unroll
        for (int ni = 0; ni < 4; ++ni) {
          int Cc = wc * 64 + ni * 16 + lr;
          S1[R * 128 + Cc] = (__bf16)fmaxf(acc[mi][ni][r] + b1[Cc], 0.f);
        }
      }
  }
  __syncthreads();

  // sp2 = relu(sp1 @ W2^T + b2): 64x256, K=128. wave: 32 rows x 128 cols
  {
    f32x4 acc[2][8] = {};
    #pragma unroll
    for (int ks = 0; ks < 4; ++ks) {
      bf16x8 af[2];
      #pragma unroll
      for (int mi = 0; mi < 2; ++mi)
        af[mi] = *(const bf16x8*)&S1[(wr * 32 + mi * 16 + lr) * 128 + ks * 32 + lg * 8];
      #pragma unroll
      for (int ni = 0; ni < 8; ++ni) {
        bf16x8 bf = *(const bf16x8*)(SpW2t + (size_t)(wc * 128 + ni * 16 + lr) * 128 + ks * 32 + lg * 8);
        #pragma unroll
        for (int mi = 0; mi < 2; ++mi)
          acc[mi][ni] = __builtin_amdgcn_mfma_f32_16x16x32_bf16(af[mi], bf, acc[mi][ni], 0, 0, 0);
      }
    }
    #pragma unroll
    for (int mi = 0; mi < 2; ++mi)
      #pragma unroll
      for (int r = 0; r < 4; ++r) {
        int R = m0 + wr * 32 + mi * 16 + lg * 4 + r;
        #pragma unroll
        for (int ni = 0; ni < 8; ++ni) {
          int Cc = wc * 128 + ni * 16 + lr;
          sp2out[(size_t)R * 256 + Cc] = (__bf16)fmaxf(acc[mi][ni][r] + b2[Cc], 0.f);
        }
      }
  }
}

// ---------------- generic MFMA GEMM (m97 structure), XCD-grouped 1-D swizzle ----------------
// Requires M = 16384 (128 m-blocks), N = 1024 (8 n-blocks): grid 1024.
// Each XCD (b&7) owns 16 A-panels; its 8 n-blocks per panel are consecutive -> A stays in L2.
template <int EPI>  // 0 relu+bias->bf16; 1 bias->bf16
__global__ __launch_bounds__(256)
void gemm_bt(const __bf16* __restrict__ A, const __bf16* __restrict__ Bt,
             const float* __restrict__ bias, void* __restrict__ C,
             int N, int K) {
  __shared__ __align__(16) __bf16 As[128 * 64];
  __shared__ __align__(16) __bf16 Bs[128 * 64];
  const int t = threadIdx.x;
  const int lane = t & 63, wv = t >> 6;
  const int wr = wv >> 1, wc = wv & 1;
  const int lr = lane & 15, lg = lane >> 4;
  const int lrow = lane >> 3, lcol = (lane & 7) << 3;
  const int b = blockIdx.x;
  const int xcd = b & 7, seq = b >> 3;
  const int m0 = (xcd * 16 + (seq >> 3)) * 128;
  const int n0 = (seq & 7) * 128;

  f32x4 acc[4][4] = {};
  const int nkt = K >> 6;
  for (int kt = 0; kt < nkt; ++kt) {
    const int k0 = kt << 6;
    #pragma unroll
    for (int it = 0; it < 4; ++it) {
      const int rbase = wv * 32 + it * 8;
      gload16(A + (size_t)(m0 + rbase + lrow) * K + k0 + lcol, &As[rbase * 64]);
      gload16(Bt + (size_t)(n0 + rbase + lrow) * K + k0 + lcol, &Bs[rbase * 64]);
    }
    __syncthreads();
    #pragma unroll
    for (int ks = 0; ks < 2; ++ks) {
      bf16x8 af[4], bfr[4];
      #pragma unroll
      for (int mi = 0; mi < 4; ++mi)
        af[mi] = *(const bf16x8*)&As[(wr * 64 + mi * 16 + lr) * 64 + ks * 32 + lg * 8];
      #pragma unroll
      for (int ni = 0; ni < 4; ++ni)
        bfr[ni] = *(const bf16x8*)&Bs[(wc * 64 + ni * 16 + lr) * 64 + ks * 32 + lg * 8];
      #pragma unroll
      for (int mi = 0; mi < 4; ++mi)
        #pragma unroll
        for (int ni = 0; ni < 4; ++ni)
          acc[mi][ni] = __builtin_amdgcn_mfma_f32_16x16x32_bf16(af[mi], bfr[ni], acc[mi][ni], 0, 0, 0);
    }
    __syncthreads();
  }
  #pragma unroll
  for (int mi = 0; mi < 4; ++mi)
    #pragma unroll
    for (int r = 0; r < 4; ++r) {
      int R = m0 + wr * 64 + mi * 16 + lg * 4 + r;
      #pragma unroll
      for (int ni = 0; ni < 4; ++ni) {
        int Cc = n0 + wc * 64 + ni * 16 + lr;
        float v = acc[mi][ni][r] + bias[Cc];
        if constexpr (EPI == 0) v = fmaxf(v, 0.f);
        ((__bf16*)C)[(size_t)R * N + Cc] = (__bf16)v;
      }
    }
}

// ---------------- gemm_u1: H1 + N1 (32x128 tiles, grid (17,8)) ----------------
__global__ __launch_bounds__(256)
void gemm_u1(const __bf16* __restrict__ hn_b, const __bf16* __restrict__ node_b,
             const __bf16* __restrict__ W1at, const __bf16* __restrict__ W1bt,
             const float* __restrict__ b1, float* __restrict__ H1, float* __restrict__ N1) {
  __shared__ __align__(16) __bf16 As[32 * 64];
  __shared__ __align__(16) __bf16 Bs[128 * 64];
  const int t = threadIdx.x;
  const int lane = t & 63, wv = t >> 6;
  const int wr = wv >> 1, wc = wv & 1;
  const int lr = lane & 15, lg = lane >> 4;
  const int lrow = lane >> 3, lcol = (lane & 7) << 3;
  const bool isH = (blockIdx.x == 0);
  const __bf16* Ap = isH ? hn_b : node_b + (size_t)(blockIdx.x - 1) * 32 * 1024;
  const __bf16* Bp = isH ? W1at : W1bt;
  const int n0 = blockIdx.y * 128;

  f32x4 acc[4] = {};
  for (int kt = 0; kt < 16; ++kt) {
    const int k0 = kt << 6;
    gload16(Ap + (size_t)(wv * 8 + lrow) * 1024 + k0 + lcol, &As[(wv * 8) * 64]);
    #pragma unroll
    for (int it = 0; it < 4; ++it) {
      const int rbase = wv * 32 + it * 8;
      gload16(Bp + (size_t)(n0 + rbase + lrow) * 1024 + k0 + lcol, &Bs[rbase * 64]);
    }
    __syncthreads();
    #pragma unroll
    for (int ks = 0; ks < 2; ++ks) {
      bf16x8 af = *(const bf16x8*)&As[(wr * 16 + lr) * 64 + ks * 32 + lg * 8];
      #pragma unroll
      for (int ni = 0; ni < 4; ++ni) {
        bf16x8 bfr = *(const bf16x8*)&Bs[(wc * 64 + ni * 16 + lr) * 64 + ks * 32 + lg * 8];
        acc[ni] = __builtin_amdgcn_mfma_f32_16x16x32_bf16(af, bfr, acc[ni], 0, 0, 0);
      }
    }
    __syncthreads();
  }
  #pragma unroll
  for (int ni = 0; ni < 4; ++ni)
    #pragma unroll
    for (int r = 0; r < 4; ++r) {
      int R = wr * 16 + lg * 4 + r;
      int Cc = n0 + wc * 64 + ni * 16 + lr;
      float v = acc[ni][r];
      if (isH) H1[(size_t)R * 1024 + Cc] = v + b1[Cc];
      else     N1[((size_t)(blockIdx.x - 1) * 32 + R) * 1024 + Cc] = v;
    }
}

// ---------------- build_hdn (wide streaming, 8192 blocks) ----------------
__global__ void build_hdn(const __bf16* __restrict__ u2, const float* __restrict__ H1,
                          const float* __restrict__ N1, __bf16* __restrict__ hdn) {
  int gid = blockIdx.x * 256 + threadIdx.x;
  int p = gid >> 7, c8 = (gid & 127) << 3;
  int i = p >> 9, j = p & 511;
  bf16x8 u = *(const bf16x8*)(u2 + (size_t)p * 1024 + c8);
  const float* hp = H1 + (size_t)i * 1024 + c8;
  const float* np = N1 + (size_t)j * 1024 + c8;
  f32x4 h0 = *(const f32x4*)hp, h1 = *(const f32x4*)(hp + 4);
  f32x4 n0 = *(const f32x4*)np, n1 = *(const f32x4*)(np + 4);
  bf16x8 o;
  #pragma unroll
  for (int e = 0; e < 4; ++e) {
    o[e]     = (__bf16)fmaxf((h0[e] + n0[e]) * (float)u[e], 0.f);
    o[4 + e] = (__bf16)fmaxf((h1[e] + n1[e]) * (float)u[4 + e], 0.f);
  }
  *(bf16x8*)(hdn + (size_t)p * 1024 + c8) = o;
}

// ---------------- gemm_adj: m97 GEMM + adjacency-dot epilogue, XCD swizzle ----------------
// grid 1024 1-D; plane h = n-block index (8 planes)
__global__ __launch_bounds__(256)
void gemm_adj(const __bf16* __restrict__ hdn, const __bf16* __restrict__ W3t,
              const float* __restrict__ b3s, const float* __restrict__ adjw,
              float* __restrict__ adjpre8) {
  __shared__ __align__(16) __bf16 As[128 * 64];
  __shared__ __align__(16) __bf16 Bs[128 * 64];
  __shared__ float redbuf[2][128];
  const int t = threadIdx.x;
  const int lane = t & 63, wv = t >> 6;
  const int wr = wv >> 1, wc = wv & 1;
  const int lr = lane & 15, lg = lane >> 4;
  const int lrow = lane >> 3, lcol = (lane & 7) << 3;
  const int b = blockIdx.x;
  const int xcd = b & 7, seq = b >> 3;
  const int m0 = (xcd * 16 + (seq >> 3)) * 128;
  const int h = seq & 7, c0 = h * 128;

  f32x4 acc[4][4] = {};
  for (int kt = 0; kt < 16; ++kt) {
    const int k0 = kt << 6;
    #pragma unroll
    for (int it = 0; it < 4; ++it) {
      const int rbase = wv * 32 + it * 8;
      gload16(hdn + (size_t)(m0 + rbase + lrow) * 1024 + k0 + lcol, &As[rbase * 64]);
      gload16(W3t + (size_t)(c0 + rbase + lrow) * 1024 + k0 + lcol, &Bs[rbase * 64]);
    }
    __syncthreads();
    #pragma unroll
    for (int ks = 0; ks < 2; ++ks) {
      bf16x8 af[4], bfr[4];
      #pragma unroll
      for (int mi = 0; mi < 4; ++mi)
        af[mi] = *(const bf16x8*)&As[(wr * 64 + mi * 16 + lr) * 64 + ks * 32 + lg * 8];
      #pragma unroll
      for (int ni = 0; ni < 4; ++ni)
        bfr[ni] = *(const bf16x8*)&Bs[(wc * 64 + ni * 16 + lr) * 64 + ks * 32 + lg * 8];
      #pragma unroll
      for (int mi = 0; mi < 4; ++mi)
        #pragma unroll
        for (int ni = 0; ni < 4; ++ni)
          acc[mi][ni] = __builtin_amdgcn_mfma_f32_16x16x32_bf16(af[mi], bfr[ni], acc[mi][ni], 0, 0, 0);
    }
    __syncthreads();
  }

  float b3v[4], awv[4];
  #pragma unroll
  for (int ni = 0; ni < 4; ++ni) {
    int Cc = c0 + wc * 64 + ni * 16 + lr;
    b3v[ni] = b3s[Cc];
    awv[ni] = adjw[Cc];
  }
  #pragma unroll
  for (int mi = 0; mi < 4; ++mi)
    #pragma unroll
    for (int r = 0; r < 4; ++r) {
      float s = 0.f;
      #pragma unroll
      for (int ni = 0; ni < 4; ++ni)
        s += fmaxf(acc[mi][ni][r] + b3v[ni], 0.f) * awv[ni];
      s += __shfl_xor(s, 1);
      s += __shfl_xor(s, 2);
      s += __shfl_xor(s, 4);
      s += __shfl_xor(s, 8);
      if (lr == 0)
        redbuf[wc][wr * 64 + mi * 16 + lg * 4 + r] = s;
    }
  __syncthreads();
  if (t < 128)
    adjpre8[(size_t)h * 16384 + m0 + t] = redbuf[0][t] + redbuf[1][t];
}

// ---------------- msg + LN merged (ping-pong, 8 planes) ----------------
__global__ void msgln(const float* __restrict__ adjpre8, const float* __restrict__ adjb,
                      const float* __restrict__ node_in_f, const float* __restrict__ hn_in_f,
                      const float* __restrict__ lno_g, const float* __restrict__ lno_b,
                      const float* __restrict__ lnh_g, const float* __restrict__ lnh_b,
                      float* __restrict__ node_out_f, float* __restrict__ hn_out_f,
                      __bf16* __restrict__ node_bb, __bf16* __restrict__ hn_bb) {
  __shared__ float adjrow[512];
  __shared__ float sbuf[4];
  const int row = blockIdx.x, t = threadIdx.x;
  const float ab = adjb[0];
  const bool isH = row < 32;
  f32x4 msg = {0.f, 0.f, 0.f, 0.f};
  if (isH) {
    const int i = row;
    float s0 = 0.f, s1 = 0.f;
    #pragma unroll
    for (int h = 0; h < 8; ++h) {
      s0 += adjpre8[(size_t)h * 16384 + i * 512 + t];
      s1 += adjpre8[(size_t)h * 16384 + i * 512 + 256 + t];
    }
    adjrow[t] = fmaxf(s0 + ab, 0.f);
    adjrow[256 + t] = fmaxf(s1 + ab, 0.f);
    __syncthreads();
    for (int j = 0; j < 512; ++j)
      msg += adjrow[j] * ((const f32x4*)node_in_f)[j * 256 + t];
  } else {
    const int j = row - 32;
    int i = t >> 3, hh = t & 7;
    float v = adjpre8[(size_t)hh * 16384 + i * 512 + j];
    v += __shfl_xor(v, 1);
    v += __shfl_xor(v, 2);
    v += __shfl_xor(v, 4);
    if (hh == 0) adjrow[i] = fmaxf(v + ab, 0.f);
    __syncthreads();
    for (int i2 = 0; i2 < 32; ++i2)
      msg += adjrow[i2] * ((const f32x4*)hn_in_f)[i2 * 256 + t];
  }
  const int r = isH ? row : row - 32;
  const float* X = (isH ? hn_in_f : node_in_f) + (size_t)r * 1024;
  const float* g = isH ? lnh_g : lno_g;
  const float* bb = isH ? lnh_b : lno_b;
  float* Xo = (isH ? hn_out_f : node_out_f) + (size_t)r * 1024;
  __bf16* Xb = (isH ? hn_bb : node_bb) + (size_t)r * 1024;

  f32x4 x = ((const f32x4*)X)[t];
  f32x4 y;
  #pragma unroll
  for (int e = 0; e < 4; ++e) y[e] = x[e] * GAMA_F + (1.0f - GAMA_F) * msg[e];
  float s = y[0] + y[1] + y[2] + y[3];
  #pragma unroll
  for (int mm = 32; mm >= 1; mm >>= 1) s += __shfl_xor(s, mm);
  if ((t & 63) == 0) sbuf[t >> 6] = s;
  __syncthreads();
  float mean = (sbuf[0] + sbuf[1] + sbuf[2] + sbuf[3]) * (1.0f / 1024.0f);
  __syncthreads();
  f32x4 d;
  #pragma unroll
  for (int e = 0; e < 4; ++e) d[e] = y[e] - mean;
  float sq = d[0] * d[0] + d[1] * d[1] + d[2] * d[2] + d[3] * d[3];
  #pragma unroll
  for (int mm = 32; mm >= 1; mm >>= 1) sq += __shfl_xor(sq, mm);
  if ((t & 63) == 0) sbuf[t >> 6] = sq;
  __syncthreads();
  float var = (sbuf[0] + sbuf[1] + sbuf[2] + sbuf[3]) * (1.0f / 1024.0f);
  float inv = rsqrtf(var + LNEPS);
  f32x4 gg = ((const f32x4*)g)[t];
  f32x4 bv = ((const f32x4*)bb)[t];
  f32x4 o;
  bf16x4 ob;
  #pragma unroll
  for (int e = 0; e < 4; ++e) { o[e] = d[e] * inv * gg[e] + bv[e]; ob[e] = (__bf16)o[e]; }
  ((f32x4*)Xo)[t] = o;
  *(bf16x4*)(Xb + t * 4) = ob;
}

// ---------------- gather ----------------
__global__ void gather_k(const float* __restrict__ hn, const float* __restrict__ node,
                         const float* __restrict__ adjpre8, const float* __restrict__ adjb,
                         float* __restrict__ out) {
  int p = blockIdx.x, t = threadIdx.x;
  int i = p >> 9, j = p & 511;
  if (i == j) return;
  int m = p - (p + 512) / 513;
  float* out0 = out;
  float* out1 = out + (size_t)16352 * 1024;
  float* out2 = out1 + (size_t)16352 * 1024;
  ((f32x4*)out0)[(size_t)m * 256 + t] = ((const f32x4*)hn)[i * 256 + t];
  ((f32x4*)out1)[(size_t)m * 256 + t] = ((const f32x4*)node)[j * 256 + t];
  if (t == 0) {
    float s = adjb[0];
    #pragma unroll
    for (int h = 0; h < 8; ++h) s += adjpre8[(size_t)h * 16384 + p];
    out2[m] = fmaxf(s, 0.f);
    out2[16352 + m] = (float)i;
    out2[2 * 16352 + m] = (float)j;
  }
}

// ---------------- host ----------------
extern "C" void kernel_launch(void* const* d_in, const int* in_sizes, int n_in,
                              void* d_out, int out_size, void* d_ws, size_t ws_size,
                              hipStream_t stream) {
  const float* node_in = (const float*)d_in[1];
  const float* coords  = (const float*)d_in[2];
  const void*  imh     = d_in[3];
  const void*  imw     = d_in[4];
  const float* sp_w1 = (const float*)d_in[5];
  const float* sp_b1 = (const float*)d_in[6];
  const float* sp_w2 = (const float*)d_in[7];
  const float* sp_b2 = (const float*)d_in[8];
  const float* sp_w3 = (const float*)d_in[9];
  const float* sp_b3 = (const float*)d_in[10];
  const float* att_w1 = (const float*)d_in[11];
  const float* att_b1 = (const float*)d_in[12];
  const float* att_w2 = (const float*)d_in[13];
  const float* att_b2 = (const float*)d_in[14];
  const float* att_w3 = (const float*)d_in[15];
  const float* att_b3 = (const float*)d_in[16];
  const float* adj_w  = (const float*)d_in[17];
  const float* adj_b  = (const float*)d_in[18];
  const float* lnh_g  = (const float*)d_in[19];
  const float* lnh_b  = (const float*)d_in[20];
  const float* lno_g  = (const float*)d_in[21];
  const float* lno_b  = (const float*)d_in[22];

  char* w = (char*)d_ws;
  size_t off = 0;
  auto alloc = [&](size_t bytes) -> char* {
    char* p = w + off;
    off += (bytes + 255) & ~(size_t)255;
    return p;
  };
  __bf16* W1at  = (__bf16*)alloc((size_t)1024 * 1024 * 2);
  __bf16* W1bt  = (__bf16*)alloc((size_t)1024 * 1024 * 2);
  __bf16* W2t   = (__bf16*)alloc((size_t)1024 * 1024 * 2);
  __bf16* W3t   = (__bf16*)alloc((size_t)1024 * 1024 * 2);
  __bf16* SpW1t = (__bf16*)alloc(128 * 64 * 2);
  __bf16* SpW2t = (__bf16*)alloc(256 * 128 * 2);
  __bf16* SpW3t = (__bf16*)alloc(1024 * 256 * 2);
  float*  b3s   = (float*)alloc(1024 * 4);
  __bf16* f36   = (__bf16*)alloc((size_t)16384 * 64 * 2);
  __bf16* sp2   = (__bf16*)alloc((size_t)16384 * 256 * 2);
  __bf16* spb   = (__bf16*)alloc((size_t)16384 * 1024 * 2);  // reused as hdn after u2
  __bf16* u2    = (__bf16*)alloc((size_t)16384 * 1024 * 2);
  float*  H1    = (float*)alloc((size_t)32 * 1024 * 4);
  float*  N1    = (float*)alloc((size_t)512 * 1024 * 4);
  float*  adjpre8 = (float*)alloc((size_t)8 * 16384 * 4);
  float*  node_f0 = (float*)alloc((size_t)512 * 1024 * 4);
  float*  node_f1 = (float*)alloc((size_t)512 * 1024 * 4);
  float*  hn_f0   = (float*)alloc((size_t)32 * 1024 * 4);
  float*  hn_f1   = (float*)alloc((size_t)32 * 1024 * 4);
  __bf16* node_b  = (__bf16*)alloc((size_t)512 * 1024 * 2);
  __bf16* hn_b    = (__bf16*)alloc((size_t)32 * 1024 * 2);
  if (off > ws_size) return;  // fail loud rather than corrupt

  // SpW3t here is [o][k] with K=256; gemm for spb needs M=16384,N=1024,K=256 — use
  // the swizzled gemm_bt (requires N=1024, holds).
  prep_mega<<<3072, 256, 0, stream>>>(att_w1, att_w2, att_w3, sp_w3, sp_w1, sp_w2, att_b3,
                                      node_in, coords, imh, imw,
                                      W1at, W1bt, W2t, W3t, SpW3t, SpW1t, SpW2t, b3s,
                                      node_f0, node_b, hn_f0, hn_b, f36);
  mlp_head<<<256, 256, 0, stream>>>(f36, SpW1t, SpW2t, sp_b1, sp_b2, sp2);
  gemm_bt<0><<<1024, 256, 0, stream>>>(sp2, SpW3t, sp_b3, spb, 1024, 256);
  gemm_bt<1><<<1024, 256, 0, stream>>>(spb, W2t, att_b2, u2, 1024, 1024);

  __bf16* hdn = spb;  // spb dead after u2
  // iter 1: read f0 -> write f1
  gemm_u1<<<dim3(17, 8), 256, 0, stream>>>(hn_b, node_b, W1at, W1bt, att_b1, H1, N1);
  build_hdn<<<8192, 256, 0, stream>>>(u2, H1, N1, hdn);
  gemm_adj<<<1024, 256, 0, stream>>>(hdn, W3t, b3s, adj_w, adjpre8);
  msgln<<<544, 256, 0, stream>>>(adjpre8, adj_b, node_f0, hn_f0,
                                 lno_g, lno_b, lnh_g, lnh_b,
                                 node_f1, hn_f1, node_b, hn_b);
  // iter 2: read f1 -> write f0
  gemm_u1<<<dim3(17, 8), 256, 0, stream>>>(hn_b, node_b, W1at, W1bt, att_b1, H1, N1);
  build_hdn<<<8192, 256, 0, stream>>>(u2, H1, N1, hdn);
  gemm_adj<<<1024, 256, 0, stream>>>(hdn, W3t, b3s, adj_w, adjpre8);
  msgln<<<544, 256, 0, stream>>>(adjpre8, adj_b, node_f1, hn_f1,
                                 lno_g, lno_b, lnh_g, lnh_b,
                                 node_f0, hn_f0, node_b, hn_b);

  gather_k<<<16384, 256, 0, stream>>>(hn_f0, node_f0, adjpre8, adj_b, (float*)d_out);
}

// Round 7
// 470.672 us; speedup vs baseline: 1.2709x; 1.0653x over previous
//
#include <hip/hip_runtime.h>
#include <hip/hip_bf16.h>

// GCN_55602646614506 — round 6 resubmit (r6 never ran: GPU acquisition timeout).
// r5 post-mortem: mlp_head staging strided wrong (absmax 0.016->4.4, passed by luck) —
// FIXED. Big change: u2 + adjacency GEMMs ported to 256^2 8-phase-lite schedule
// (512 thr / 8 waves, dbuf LDS 128KB, raw s_barrier phases, front-loaded
// global_load_lds staging, vmcnt(0) only at K-tile boundary, setprio around MFMA).
// Adjacency partial planes 8 -> 4. Everything else from r5 kept.

typedef __attribute__((ext_vector_type(4))) float  f32x4;
typedef __attribute__((ext_vector_type(8))) __bf16 bf16x8;
typedef __attribute__((ext_vector_type(4))) __bf16 bf16x4;

#define FEPS 1e-10f
#define LNEPS 1e-5f
#define GAMA_F 0.9f

__device__ __forceinline__ void gload16(const void* g, void* l) {
  __builtin_amdgcn_global_load_lds(
      (const __attribute__((address_space(1))) void*)g,
      (__attribute__((address_space(3))) void*)l, 16, 0, 0);
}

__device__ __forceinline__ float read_dim(const void* p) {
  int iv = *(const int*)p;
  if (iv > 0 && iv < (1 << 20)) return (float)iv;
  return *(const float*)p;
}

// ---------------- prep_mega ----------------
__global__ void prep_mega(const float* __restrict__ w1, const float* __restrict__ w2,
                          const float* __restrict__ w3, const float* __restrict__ spw3,
                          const float* __restrict__ spw1, const float* __restrict__ spw2,
                          const float* __restrict__ b3,
                          const float* __restrict__ node_in,
                          const float* __restrict__ coords,
                          const void* __restrict__ imh, const void* __restrict__ imw,
                          __bf16* __restrict__ W1at, __bf16* __restrict__ W1bt,
                          __bf16* __restrict__ W2t, __bf16* __restrict__ W3t,
                          __bf16* __restrict__ SpW3t,
                          __bf16* __restrict__ SpW1t, __bf16* __restrict__ SpW2t,
                          float* __restrict__ b3s,
                          float* __restrict__ node_f, __bf16* __restrict__ node_b,
                          float* __restrict__ hn_f, __bf16* __restrict__ hn_b,
                          __bf16* __restrict__ f36) {
  __shared__ float tile[64][65];
  const int b = blockIdx.x, t = threadIdx.x;
  const int tc = t & 63, tr = t >> 6;
  if (b < 256) {
    const int c = b >> 4, d0 = (b & 15) << 6;
    #pragma unroll
    for (int pass = 0; pass < 2; ++pass) {
      const float* src = w1 + (size_t)c * 131072 + (size_t)(d0 + pass * 1024) * 64;
      __bf16* dst = pass ? W1bt : W1at;
      if (pass) __syncthreads();
      #pragma unroll
      for (int q = 0; q < 16; ++q) {
        int dd = q * 4 + tr;
        tile[dd][tc] = src[dd * 64 + tc];
      }
      __syncthreads();
      #pragma unroll
      for (int q = 0; q < 16; ++q) {
        int kk = q * 4 + tr;
        dst[(size_t)(c * 64 + kk) * 1024 + d0 + tc] = (__bf16)tile[tc][kk];
      }
    }
  } else if (b < 512) {
    const int bb = b - 256, c = bb >> 4, s0 = (bb & 15) << 6;
    const float* src = w2 + (size_t)c * 65536 + (size_t)s0 * 64;
    #pragma unroll
    for (int q = 0; q < 16; ++q) {
      int ss = q * 4 + tr;
      tile[ss][tc] = src[ss * 64 + tc];
    }
    __syncthreads();
    #pragma unroll
    for (int q = 0; q < 16; ++q) {
      int kk = q * 4 + tr;
      W2t[(size_t)(c * 64 + kk) * 1024 + s0 + tc] = (__bf16)tile[tc][kk];
    }
  } else if (b < 768) {
    const int bb = b - 512, c = bb >> 4, o0 = (bb & 15) << 6;
    const float* src = w3 + (size_t)c * 65536;
    #pragma unroll
    for (int q = 0; q < 16; ++q) {
      int kk = q * 4 + tr;
      tile[kk][tc] = src[kk * 1024 + o0 + tc];
    }
    __syncthreads();
    #pragma unroll
    for (int q = 0; q < 16; ++q) {
      int oo = q * 4 + tr;
      W3t[(size_t)(o0 + oo) * 1024 + c * 64 + tc] = (__bf16)tile[tc][oo];
    }
  } else if (b < 832) {
    const int bb = b - 768, o0 = (bb >> 2) << 6, k0 = (bb & 3) << 6;
    #pragma unroll
    for (int q = 0; q < 16; ++q) {
      int kk = q * 4 + tr;
      tile[kk][tc] = spw3[(size_t)(k0 + kk) * 1024 + o0 + tc];
    }
    __syncthreads();
    #pragma unroll
    for (int q = 0; q < 16; ++q) {
      int oo = q * 4 + tr;
      SpW3t[(size_t)(o0 + oo) * 256 + k0 + tc] = (__bf16)tile[tc][oo];
    }
  } else if (b < 960) {
    int gid = (b - 832) * 256 + t;
    if (gid < 8192) {
      int n = gid >> 6, k = gid & 63;
      SpW1t[gid] = (k < 36) ? (__bf16)spw1[k * 128 + n] : (__bf16)0.f;
    }
    {
      int n = gid >> 7, k = gid & 127;
      SpW2t[gid] = (__bf16)spw2[k * 256 + n];
    }
    if (gid < 1024) {
      float s = 0.f;
      for (int cc = 0; cc < 16; ++cc) s += b3[cc * 1024 + gid];
      b3s[gid] = s;
    }
  } else if (b < 3008) {
    int gid = (b - 960) * 256 + t;
    float v = node_in[gid];
    node_f[gid] = v;
    node_b[gid] = (__bf16)v;
    if (gid < 32 * 1024) { hn_f[gid] = v; hn_b[gid] = (__bf16)v; }
  } else {
    int p = (b - 3008) * 256 + t;
    int i = p >> 9, j = p & 511;
    float H = read_dim(imh), W = read_dim(imw);
    f32x4 b1 = ((const f32x4*)coords)[i];
    f32x4 b2 = ((const f32x4*)coords)[j];
    float c1x = (b1[0] + b1[2]) * 0.5f, c1y = (b1[1] + b1[3]) * 0.5f;
    float c2x = (b2[0] + b2[2]) * 0.5f, c2y = (b2[1] + b2[3]) * 0.5f;
    float b1w = b1[2] - b1[0], b1h = b1[3] - b1[1];
    float b2w = b2[2] - b2[0], b2h = b2[3] - b2[1];
    float dx = fabsf(c2x - c1x) / (b1w + FEPS);
    float dy = fabsf(c2y - c1y) / (b1h + FEPS);
    float ltx = fmaxf(b1[0], b2[0]), lty = fmaxf(b1[1], b2[1]);
    float rbx = fminf(b1[2], b2[2]), rby = fminf(b1[3], b2[3]);
    float inter = fmaxf(rbx - ltx, 0.f) * fmaxf(rby - lty, 0.f);
    float a1 = b1w * b1h, a2 = b2w * b2h;
    float iou = inter / (a1 + a2 - inter);
    float f[18];
    f[0] = c1x / W;  f[1] = c1y / H;  f[2] = c2x / W;  f[3] = c2y / H;
    f[4] = b1w / W;  f[5] = b1h / H;  f[6] = b2w / W;  f[7] = b2h / H;
    f[8] = a1 / (H * W); f[9] = a2 / (H * W); f[10] = a2 / (a1 + FEPS);
    f[11] = b1w / (b1h + FEPS); f[12] = b2w / (b2h + FEPS); f[13] = iou;
    f[14] = (c2x > c1x) ? dx : 0.f; f[15] = (c2x < c1x) ? dx : 0.f;
    f[16] = (c2y > c1y) ? dy : 0.f; f[17] = (c2y < c1y) ? dy : 0.f;
    __bf16 o[64];
    #pragma unroll
    for (int q = 0; q < 18; ++q) { o[q] = (__bf16)f[q]; o[18 + q] = (__bf16)logf(f[q] + FEPS); }
    #pragma unroll
    for (int q = 36; q < 64; ++q) o[q] = (__bf16)0.f;
    bf16x8* dst = (bf16x8*)(f36 + (size_t)p * 64);
    #pragma unroll
    for (int q = 0; q < 8; ++q) dst[q] = *(bf16x8*)&o[q * 8];
  }
}

// ---------------- mlp_head (staging fixed: t*8 element stride, both halves in-bounds) ----------------
__global__ __launch_bounds__(256)
void mlp_head(const __bf16* __restrict__ f36, const __bf16* __restrict__ SpW1t,
              const __bf16* __restrict__ SpW2t, const float* __restrict__ b1,
              const float* __restrict__ b2, __bf16* __restrict__ sp2out) {
  __shared__ __align__(16) __bf16 Af[64 * 64];    // 8KB
  __shared__ __align__(16) __bf16 S1[64 * 128];   // 16KB
  const int t = threadIdx.x;
  const int lane = t & 63, wv = t >> 6;
  const int wr = wv >> 1, wc = wv & 1;
  const int lr = lane & 15, lg = lane >> 4;
  const int m0 = blockIdx.x * 64;

  gload16(f36 + (size_t)m0 * 64 + t * 8, &Af[t * 8]);
  gload16(f36 + (size_t)m0 * 64 + 2048 + t * 8, &Af[2048 + t * 8]);
  __syncthreads();

  {
    f32x4 acc[2][4] = {};
    #pragma unroll
    for (int ks = 0; ks < 2; ++ks) {
      bf16x8 af[2], bf[4];
      #pragma unroll
      for (int mi = 0; mi < 2; ++mi)
        af[mi] = *(const bf16x8*)&Af[(wr * 32 + mi * 16 + lr) * 64 + ks * 32 + lg * 8];
      #pragma unroll
      for (int ni = 0; ni < 4; ++ni)
        bf[ni] = *(const bf16x8*)(SpW1t + (size_t)(wc * 64 + ni * 16 + lr) * 64 + ks * 32 + lg * 8);
      #pragma unroll
      for (int mi = 0; mi < 2; ++mi)
        #pragma unroll
        for (int ni = 0; ni < 4; ++ni)
          acc[mi][ni] = __builtin_amdgcn_mfma_f32_16x16x32_bf16(af[mi], bf[ni], acc[mi][ni], 0, 0, 0);
    }
    #pragma unroll
    for (int mi = 0; mi < 2; ++mi)
      #pragma unroll
      for (int r = 0; r < 4; ++r) {
        int R = wr * 32 + mi * 16 + lg * 4 + r;
        #pragma unroll
        for (int ni = 0; ni < 4; ++ni) {
          int Cc = wc * 64 + ni * 16 + lr;
          S1[R * 128 + Cc] = (__bf16)fmaxf(acc[mi][ni][r] + b1[Cc], 0.f);
        }
      }
  }
  __syncthreads();

  {
    f32x4 acc[2][8] = {};
    #pragma unroll
    for (int ks = 0; ks < 4; ++ks) {
      bf16x8 af[2];
      #pragma unroll
      for (int mi = 0; mi < 2; ++mi)
        af[mi] = *(const bf16x8*)&S1[(wr * 32 + mi * 16 + lr) * 128 + ks * 32 + lg * 8];
      #pragma unroll
      for (int ni = 0; ni < 8; ++ni) {
        bf16x8 bf = *(const bf16x8*)(SpW2t + (size_t)(wc * 128 + ni * 16 + lr) * 128 + ks * 32 + lg * 8);
        #pragma unroll
        for (int mi = 0; mi < 2; ++mi)
          acc[mi][ni] = __builtin_amdgcn_mfma_f32_16x16x32_bf16(af[mi], bf, acc[mi][ni], 0, 0, 0);
      }
    }
    #pragma unroll
    for (int mi = 0; mi < 2; ++mi)
      #pragma unroll
      for (int r = 0; r < 4; ++r) {
        int R = m0 + wr * 32 + mi * 16 + lg * 4 + r;
        #pragma unroll
        for (int ni = 0; ni < 8; ++ni) {
          int Cc = wc * 128 + ni * 16 + lr;
          sp2out[(size_t)R * 256 + Cc] = (__bf16)fmaxf(acc[mi][ni][r] + b2[Cc], 0.f);
        }
      }
  }
}

// ---------------- gemm_bt 128^2 (kept for spb, K=256), XCD swizzle ----------------
template <int EPI>  // 0 relu+bias->bf16
__global__ __launch_bounds__(256)
void gemm_bt(const __bf16* __restrict__ A, const __bf16* __restrict__ Bt,
             const float* __restrict__ bias, void* __restrict__ C,
             int N, int K) {
  __shared__ __align__(16) __bf16 As[128 * 64];
  __shared__ __align__(16) __bf16 Bs[128 * 64];
  const int t = threadIdx.x;
  const int lane = t & 63, wv = t >> 6;
  const int wr = wv >> 1, wc = wv & 1;
  const int lr = lane & 15, lg = lane >> 4;
  const int lrow = lane >> 3, lcol = (lane & 7) << 3;
  const int b = blockIdx.x;
  const int xcd = b & 7, seq = b >> 3;
  const int m0 = (xcd * 16 + (seq >> 3)) * 128;
  const int n0 = (seq & 7) * 128;

  f32x4 acc[4][4] = {};
  const int nkt = K >> 6;
  for (int kt = 0; kt < nkt; ++kt) {
    const int k0 = kt << 6;
    #pragma unroll
    for (int it = 0; it < 4; ++it) {
      const int rbase = wv * 32 + it * 8;
      gload16(A + (size_t)(m0 + rbase + lrow) * K + k0 + lcol, &As[rbase * 64]);
      gload16(Bt + (size_t)(n0 + rbase + lrow) * K + k0 + lcol, &Bs[rbase * 64]);
    }
    __syncthreads();
    #pragma unroll
    for (int ks = 0; ks < 2; ++ks) {
      bf16x8 af[4], bfr[4];
      #pragma unroll
      for (int mi = 0; mi < 4; ++mi)
        af[mi] = *(const bf16x8*)&As[(wr * 64 + mi * 16 + lr) * 64 + ks * 32 + lg * 8];
      #pragma unroll
      for (int ni = 0; ni < 4; ++ni)
        bfr[ni] = *(const bf16x8*)&Bs[(wc * 64 + ni * 16 + lr) * 64 + ks * 32 + lg * 8];
      #pragma unroll
      for (int mi = 0; mi < 4; ++mi)
        #pragma unroll
        for (int ni = 0; ni < 4; ++ni)
          acc[mi][ni] = __builtin_amdgcn_mfma_f32_16x16x32_bf16(af[mi], bfr[ni], acc[mi][ni], 0, 0, 0);
    }
    __syncthreads();
  }
  #pragma unroll
  for (int mi = 0; mi < 4; ++mi)
    #pragma unroll
    for (int r = 0; r < 4; ++r) {
      int R = m0 + wr * 64 + mi * 16 + lg * 4 + r;
      #pragma unroll
      for (int ni = 0; ni < 4; ++ni) {
        int Cc = n0 + wc * 64 + ni * 16 + lr;
        float v = acc[mi][ni][r] + bias[Cc];
        if constexpr (EPI == 0) v = fmaxf(v, 0.f);
        ((__bf16*)C)[(size_t)R * N + Cc] = (__bf16)v;
      }
    }
}

// ---------------- gemm256: 256^2 8-phase-lite (N=1024 fixed) ----------------
// EPI 1: bias -> bf16 C.   EPI 4: adjacency-dot epilogue into 4 partial planes.
// Grid 256 1-D. 512 threads = 8 waves (2 wm x 4 wn); wave tile 128x64.
template <int EPI>
__global__ __launch_bounds__(512, 2)
void gemm256(const __bf16* __restrict__ A, const __bf16* __restrict__ Bt,
             const float* __restrict__ bias, void* __restrict__ C,
             const float* __restrict__ adjw, float* __restrict__ adjpre4,
             int K) {
  __shared__ __align__(16) __bf16 As[2][256 * 64];   // 64KB
  __shared__ __align__(16) __bf16 Bs[2][256 * 64];   // 64KB
  __shared__ float redbuf[4][256];                   // 4KB (EPI==4)
  const int t = threadIdx.x;
  const int lane = t & 63;
  const int wv = t >> 6;
  const int wm = wv >> 2, wn = wv & 3;
  const int lr = lane & 15, lg = lane >> 4;
  const int b = blockIdx.x;
  const int xcd = b & 7, seq = b >> 3;               // 256 blocks: 8 xcd x 32 seq
  const int m0 = (xcd * 8 + (seq >> 2)) * 256;       // consecutive seq share m-panel
  const int n0 = (seq & 3) * 256;
  const int srow = t >> 3, scol = (t & 7) * 8;       // staging: 512thr x 16B = 8KB/chunk

  f32x4 acc[8][4] = {};
  const int nkt = K >> 6;

  // prologue: stage tile 0 into buf 0 (4 chunks each of A,B)
  #pragma unroll
  for (int c = 0; c < 4; ++c) {
    gload16(A + (size_t)(m0 + c * 64 + srow) * K + scol, &As[0][(c * 64 + srow) * 64 + scol]);
    gload16(Bt + (size_t)(n0 + c * 64 + srow) * K + scol, &Bs[0][(c * 64 + srow) * 64 + scol]);
  }
  asm volatile("s_waitcnt vmcnt(0)" ::: "memory");
  __builtin_amdgcn_s_barrier();
  __builtin_amdgcn_sched_barrier(0);

  int cur = 0;
  for (int kt = 0; kt < nkt; ++kt) {
    const int k1 = (kt + 1) << 6;
    const __bf16* Acur = &As[cur][0];
    const __bf16* Bcur = &Bs[cur][0];
    __bf16* Anxt = &As[cur ^ 1][0];
    __bf16* Bnxt = &Bs[cur ^ 1][0];
    const bool more = (kt + 1 < nkt);
    bf16x8 bfr[4][2];
    #pragma unroll
    for (int p = 0; p < 4; ++p) {
      // ds-read this phase's A sub-tile (mi = 2p, 2p+1)
      bf16x8 af[2][2];
      #pragma unroll
      for (int m = 0; m < 2; ++m) {
        const int row = wm * 128 + (2 * p + m) * 16 + lr;
        af[m][0] = *(const bf16x8*)&Acur[row * 64 + lg * 8];
        af[m][1] = *(const bf16x8*)&Acur[row * 64 + 32 + lg * 8];
      }
      if (p == 0) {
        #pragma unroll
        for (int n = 0; n < 4; ++n) {
          const int row = wn * 64 + n * 16 + lr;
          bfr[n][0] = *(const bf16x8*)&Bcur[row * 64 + lg * 8];
          bfr[n][1] = *(const bf16x8*)&Bcur[row * 64 + 32 + lg * 8];
        }
      }
      // front-loaded staging of next tile (phases 0,1 only -> boundary drain is cheap)
      if (more && p < 2) {
        #pragma unroll
        for (int cc = 0; cc < 2; ++cc) {
          const int c = p * 2 + cc;
          gload16(A + (size_t)(m0 + c * 64 + srow) * K + k1 + scol, &Anxt[(c * 64 + srow) * 64 + scol]);
          gload16(Bt + (size_t)(n0 + c * 64 + srow) * K + k1 + scol, &Bnxt[(c * 64 + srow) * 64 + scol]);
        }
      }
      __builtin_amdgcn_s_barrier();
      __builtin_amdgcn_s_setprio(1);
      #pragma unroll
      for (int ks = 0; ks < 2; ++ks)
        #pragma unroll
        for (int m = 0; m < 2; ++m)
          #pragma unroll
          for (int n = 0; n < 4; ++n)
            acc[2 * p + m][n] = __builtin_amdgcn_mfma_f32_16x16x32_bf16(
                af[m][ks], bfr[n][ks], acc[2 * p + m][n], 0, 0, 0);
      __builtin_amdgcn_s_setprio(0);
      __builtin_amdgcn_s_barrier();
    }
    if (more) {
      asm volatile("s_waitcnt vmcnt(0)" ::: "memory");  // next tile's loads landed
      __builtin_amdgcn_s_barrier();                     // ...for ALL waves
      __builtin_amdgcn_sched_barrier(0);                // rule #18: pin reads below
    }
    cur ^= 1;
  }

  if constexpr (EPI == 1) {
    #pragma unroll
    for (int mi = 0; mi < 8; ++mi)
      #pragma unroll
      for (int r = 0; r < 4; ++r) {
        const int R = m0 + wm * 128 + mi * 16 + lg * 4 + r;
        #pragma unroll
        for (int ni = 0; ni < 4; ++ni) {
          const int Cc = n0 + wn * 64 + ni * 16 + lr;
          ((__bf16*)C)[(size_t)R * 1024 + Cc] = (__bf16)(acc[mi][ni][r] + bias[Cc]);
        }
      }
  } else {
    float b3v[4], awv[4];
    #pragma unroll
    for (int ni = 0; ni < 4; ++ni) {
      const int Cc = n0 + wn * 64 + ni * 16 + lr;
      b3v[ni] = bias[Cc];
      awv[ni] = adjw[Cc];
    }
    #pragma unroll
    for (int mi = 0; mi < 8; ++mi)
      #pragma unroll
      for (int r = 0; r < 4; ++r) {
        float s = 0.f;
        #pragma unroll
        for (int ni = 0; ni < 4; ++ni)
          s += fmaxf(acc[mi][ni][r] + b3v[ni], 0.f) * awv[ni];
        s += __shfl_xor(s, 1);
        s += __shfl_xor(s, 2);
        s += __shfl_xor(s, 4);
        s += __shfl_xor(s, 8);
        if (lr == 0)
          redbuf[wn][wm * 128 + mi * 16 + lg * 4 + r] = s;
      }
    __syncthreads();
    if (t < 256) {
      const int h = seq & 3;
      adjpre4[(size_t)h * 16384 + m0 + t] =
          redbuf[0][t] + redbuf[1][t] + redbuf[2][t] + redbuf[3][t];
    }
  }
}

// ---------------- gemm_u1: H1 + N1 (32x128 tiles, grid (17,8)) ----------------
__global__ __launch_bounds__(256)
void gemm_u1(const __bf16* __restrict__ hn_b, const __bf16* __restrict__ node_b,
             const __bf16* __restrict__ W1at, const __bf16* __restrict__ W1bt,
             const float* __restrict__ b1, float* __restrict__ H1, float* __restrict__ N1) {
  __shared__ __align__(16) __bf16 As[32 * 64];
  __shared__ __align__(16) __bf16 Bs[128 * 64];
  const int t = threadIdx.x;
  const int lane = t & 63, wv = t >> 6;
  const int wr = wv >> 1, wc = wv & 1;
  const int lr = lane & 15, lg = lane >> 4;
  const int lrow = lane >> 3, lcol = (lane & 7) << 3;
  const bool isH = (blockIdx.x == 0);
  const __bf16* Ap = isH ? hn_b : node_b + (size_t)(blockIdx.x - 1) * 32 * 1024;
  const __bf16* Bp = isH ? W1at : W1bt;
  const int n0 = blockIdx.y * 128;

  f32x4 acc[4] = {};
  for (int kt = 0; kt < 16; ++kt) {
    const int k0 = kt << 6;
    gload16(Ap + (size_t)(wv * 8 + lrow) * 1024 + k0 + lcol, &As[(wv * 8) * 64]);
    #pragma unroll
    for (int it = 0; it < 4; ++it) {
      const int rbase = wv * 32 + it * 8;
      gload16(Bp + (size_t)(n0 + rbase + lrow) * 1024 + k0 + lcol, &Bs[rbase * 64]);
    }
    __syncthreads();
    #pragma unroll
    for (int ks = 0; ks < 2; ++ks) {
      bf16x8 af = *(const bf16x8*)&As[(wr * 16 + lr) * 64 + ks * 32 + lg * 8];
      #pragma unroll
      for (int ni = 0; ni < 4; ++ni) {
        bf16x8 bfr = *(const bf16x8*)&Bs[(wc * 64 + ni * 16 + lr) * 64 + ks * 32 + lg * 8];
        acc[ni] = __builtin_amdgcn_mfma_f32_16x16x32_bf16(af, bfr, acc[ni], 0, 0, 0);
      }
    }
    __syncthreads();
  }
  #pragma unroll
  for (int ni = 0; ni < 4; ++ni)
    #pragma unroll
    for (int r = 0; r < 4; ++r) {
      int R = wr * 16 + lg * 4 + r;
      int Cc = n0 + wc * 64 + ni * 16 + lr;
      float v = acc[ni][r];
      if (isH) H1[(size_t)R * 1024 + Cc] = v + b1[Cc];
      else     N1[((size_t)(blockIdx.x - 1) * 32 + R) * 1024 + Cc] = v;
    }
}

// ---------------- build_hdn ----------------
__global__ void build_hdn(const __bf16* __restrict__ u2, const float* __restrict__ H1,
                          const float* __restrict__ N1, __bf16* __restrict__ hdn) {
  int gid = blockIdx.x * 256 + threadIdx.x;
  int p = gid >> 7, c8 = (gid & 127) << 3;
  int i = p >> 9, j = p & 511;
  bf16x8 u = *(const bf16x8*)(u2 + (size_t)p * 1024 + c8);
  const float* hp = H1 + (size_t)i * 1024 + c8;
  const float* np = N1 + (size_t)j * 1024 + c8;
  f32x4 h0 = *(const f32x4*)hp, h1 = *(const f32x4*)(hp + 4);
  f32x4 n0 = *(const f32x4*)np, n1 = *(const f32x4*)(np + 4);
  bf16x8 o;
  #pragma unroll
  for (int e = 0; e < 4; ++e) {
    o[e]     = (__bf16)fmaxf((h0[e] + n0[e]) * (float)u[e], 0.f);
    o[4 + e] = (__bf16)fmaxf((h1[e] + n1[e]) * (float)u[4 + e], 0.f);
  }
  *(bf16x8*)(hdn + (size_t)p * 1024 + c8) = o;
}

// ---------------- msg + LN merged (ping-pong, 4 planes) ----------------
__global__ void msgln(const float* __restrict__ adjpre4, const float* __restrict__ adjb,
                      const float* __restrict__ node_in_f, const float* __restrict__ hn_in_f,
                      const float* __restrict__ lno_g, const float* __restrict__ lno_b,
                      const float* __restrict__ lnh_g, const float* __restrict__ lnh_b,
                      float* __restrict__ node_out_f, float* __restrict__ hn_out_f,
                      __bf16* __restrict__ node_bb, __bf16* __restrict__ hn_bb) {
  __shared__ float adjrow[512];
  __shared__ float sbuf[4];
  const int row = blockIdx.x, t = threadIdx.x;
  const float ab = adjb[0];
  const bool isH = row < 32;
  f32x4 msg = {0.f, 0.f, 0.f, 0.f};
  if (isH) {
    const int i = row;
    float s0 = 0.f, s1 = 0.f;
    #pragma unroll
    for (int h = 0; h < 4; ++h) {
      s0 += adjpre4[(size_t)h * 16384 + i * 512 + t];
      s1 += adjpre4[(size_t)h * 16384 + i * 512 + 256 + t];
    }
    adjrow[t] = fmaxf(s0 + ab, 0.f);
    adjrow[256 + t] = fmaxf(s1 + ab, 0.f);
    __syncthreads();
    for (int j = 0; j < 512; ++j)
      msg += adjrow[j] * ((const f32x4*)node_in_f)[j * 256 + t];
  } else {
    const int j = row - 32;
    int i = t >> 3, hh = t & 7;
    float v = (hh < 4) ? adjpre4[(size_t)hh * 16384 + i * 512 + j] : 0.f;
    v += __shfl_xor(v, 1);
    v += __shfl_xor(v, 2);
    v += __shfl_xor(v, 4);
    if (hh == 0) adjrow[i] = fmaxf(v + ab, 0.f);
    __syncthreads();
    for (int i2 = 0; i2 < 32; ++i2)
      msg += adjrow[i2] * ((const f32x4*)hn_in_f)[i2 * 256 + t];
  }
  const int r = isH ? row : row - 32;
  const float* X = (isH ? hn_in_f : node_in_f) + (size_t)r * 1024;
  const float* g = isH ? lnh_g : lno_g;
  const float* bb = isH ? lnh_b : lno_b;
  float* Xo = (isH ? hn_out_f : node_out_f) + (size_t)r * 1024;
  __bf16* Xb = (isH ? hn_bb : node_bb) + (size_t)r * 1024;

  f32x4 x = ((const f32x4*)X)[t];
  f32x4 y;
  #pragma unroll
  for (int e = 0; e < 4; ++e) y[e] = x[e] * GAMA_F + (1.0f - GAMA_F) * msg[e];
  float s = y[0] + y[1] + y[2] + y[3];
  #pragma unroll
  for (int mm = 32; mm >= 1; mm >>= 1) s += __shfl_xor(s, mm);
  if ((t & 63) == 0) sbuf[t >> 6] = s;
  __syncthreads();
  float mean = (sbuf[0] + sbuf[1] + sbuf[2] + sbuf[3]) * (1.0f / 1024.0f);
  __syncthreads();
  f32x4 d;
  #pragma unroll
  for (int e = 0; e < 4; ++e) d[e] = y[e] - mean;
  float sq = d[0] * d[0] + d[1] * d[1] + d[2] * d[2] + d[3] * d[3];
  #pragma unroll
  for (int mm = 32; mm >= 1; mm >>= 1) sq += __shfl_xor(sq, mm);
  if ((t & 63) == 0) sbuf[t >> 6] = sq;
  __syncthreads();
  float var = (sbuf[0] + sbuf[1] + sbuf[2] + sbuf[3]) * (1.0f / 1024.0f);
  float inv = rsqrtf(var + LNEPS);
  f32x4 gg = ((const f32x4*)g)[t];
  f32x4 bv = ((const f32x4*)bb)[t];
  f32x4 o;
  bf16x4 ob;
  #pragma unroll
  for (int e = 0; e < 4; ++e) { o[e] = d[e] * inv * gg[e] + bv[e]; ob[e] = (__bf16)o[e]; }
  ((f32x4*)Xo)[t] = o;
  *(bf16x4*)(Xb + t * 4) = ob;
}

// ---------------- gather (4 planes) ----------------
__global__ void gather_k(const float* __restrict__ hn, const float* __restrict__ node,
                         const float* __restrict__ adjpre4, const float* __restrict__ adjb,
                         float* __restrict__ out) {
  int p = blockIdx.x, t = threadIdx.x;
  int i = p >> 9, j = p & 511;
  if (i == j) return;
  int m = p - (p + 512) / 513;
  float* out0 = out;
  float* out1 = out + (size_t)16352 * 1024;
  float* out2 = out1 + (size_t)16352 * 1024;
  ((f32x4*)out0)[(size_t)m * 256 + t] = ((const f32x4*)hn)[i * 256 + t];
  ((f32x4*)out1)[(size_t)m * 256 + t] = ((const f32x4*)node)[j * 256 + t];
  if (t == 0) {
    float s = adjb[0];
    #pragma unroll
    for (int h = 0; h < 4; ++h) s += adjpre4[(size_t)h * 16384 + p];
    out2[m] = fmaxf(s, 0.f);
    out2[16352 + m] = (float)i;
    out2[2 * 16352 + m] = (float)j;
  }
}

// ---------------- host ----------------
extern "C" void kernel_launch(void* const* d_in, const int* in_sizes, int n_in,
                              void* d_out, int out_size, void* d_ws, size_t ws_size,
                              hipStream_t stream) {
  const float* node_in = (const float*)d_in[1];
  const float* coords  = (const float*)d_in[2];
  const void*  imh     = d_in[3];
  const void*  imw     = d_in[4];
  const float* sp_w1 = (const float*)d_in[5];
  const float* sp_b1 = (const float*)d_in[6];
  const float* sp_w2 = (const float*)d_in[7];
  const float* sp_b2 = (const float*)d_in[8];
  const float* sp_w3 = (const float*)d_in[9];
  const float* sp_b3 = (const float*)d_in[10];
  const float* att_w1 = (const float*)d_in[11];
  const float* att_b1 = (const float*)d_in[12];
  const float* att_w2 = (const float*)d_in[13];
  const float* att_b2 = (const float*)d_in[14];
  const float* att_w3 = (const float*)d_in[15];
  const float* att_b3 = (const float*)d_in[16];
  const float* adj_w  = (const float*)d_in[17];
  const float* adj_b  = (const float*)d_in[18];
  const float* lnh_g  = (const float*)d_in[19];
  const float* lnh_b  = (const float*)d_in[20];
  const float* lno_g  = (const float*)d_in[21];
  const float* lno_b  = (const float*)d_in[22];

  char* w = (char*)d_ws;
  size_t off = 0;
  auto alloc = [&](size_t bytes) -> char* {
    char* p = w + off;
    off += (bytes + 255) & ~(size_t)255;
    return p;
  };
  __bf16* W1at  = (__bf16*)alloc((size_t)1024 * 1024 * 2);
  __bf16* W1bt  = (__bf16*)alloc((size_t)1024 * 1024 * 2);
  __bf16* W2t   = (__bf16*)alloc((size_t)1024 * 1024 * 2);
  __bf16* W3t   = (__bf16*)alloc((size_t)1024 * 1024 * 2);
  __bf16* SpW1t = (__bf16*)alloc(128 * 64 * 2);
  __bf16* SpW2t = (__bf16*)alloc(256 * 128 * 2);
  __bf16* SpW3t = (__bf16*)alloc(1024 * 256 * 2);
  float*  b3s   = (float*)alloc(1024 * 4);
  __bf16* f36   = (__bf16*)alloc((size_t)16384 * 64 * 2);
  __bf16* sp2   = (__bf16*)alloc((size_t)16384 * 256 * 2);
  __bf16* spb   = (__bf16*)alloc((size_t)16384 * 1024 * 2);  // reused as hdn after u2
  __bf16* u2    = (__bf16*)alloc((size_t)16384 * 1024 * 2);
  float*  H1    = (float*)alloc((size_t)32 * 1024 * 4);
  float*  N1    = (float*)alloc((size_t)512 * 1024 * 4);
  float*  adjpre4 = (float*)alloc((size_t)4 * 16384 * 4);
  float*  node_f0 = (float*)alloc((size_t)512 * 1024 * 4);
  float*  node_f1 = (float*)alloc((size_t)512 * 1024 * 4);
  float*  hn_f0   = (float*)alloc((size_t)32 * 1024 * 4);
  float*  hn_f1   = (float*)alloc((size_t)32 * 1024 * 4);
  __bf16* node_b  = (__bf16*)alloc((size_t)512 * 1024 * 2);
  __bf16* hn_b    = (__bf16*)alloc((size_t)32 * 1024 * 2);
  if (off > ws_size) return;  // fail loud rather than corrupt

  prep_mega<<<3072, 256, 0, stream>>>(att_w1, att_w2, att_w3, sp_w3, sp_w1, sp_w2, att_b3,
                                      node_in, coords, imh, imw,
                                      W1at, W1bt, W2t, W3t, SpW3t, SpW1t, SpW2t, b3s,
                                      node_f0, node_b, hn_f0, hn_b, f36);
  mlp_head<<<256, 256, 0, stream>>>(f36, SpW1t, SpW2t, sp_b1, sp_b2, sp2);
  gemm_bt<0><<<1024, 256, 0, stream>>>(sp2, SpW3t, sp_b3, spb, 1024, 256);
  gemm256<1><<<256, 512, 0, stream>>>(spb, W2t, att_b2, u2, nullptr, nullptr, 1024);

  __bf16* hdn = spb;  // spb dead after u2
  // iter 1: read f0 -> write f1
  gemm_u1<<<dim3(17, 8), 256, 0, stream>>>(hn_b, node_b, W1at, W1bt, att_b1, H1, N1);
  build_hdn<<<8192, 256, 0, stream>>>(u2, H1, N1, hdn);
  gemm256<4><<<256, 512, 0, stream>>>(hdn, W3t, b3s, nullptr, adj_w, adjpre4, 1024);
  msgln<<<544, 256, 0, stream>>>(adjpre4, adj_b, node_f0, hn_f0,
                                 lno_g, lno_b, lnh_g, lnh_b,
                                 node_f1, hn_f1, node_b, hn_b);
  // iter 2: read f1 -> write f0
  gemm_u1<<<dim3(17, 8), 256, 0, stream>>>(hn_b, node_b, W1at, W1bt, att_b1, H1, N1);
  build_hdn<<<8192, 256, 0, stream>>>(u2, H1, N1, hdn);
  gemm256<4><<<256, 512, 0, stream>>>(hdn, W3t, b3s, nullptr, adj_w, adjpre4, 1024);
  msgln<<<544, 256, 0, stream>>>(adjpre4, adj_b, node_f1, hn_f1,
                                 lno_g, lno_b, lnh_g, lnh_b,
                                 node_f0, hn_f0, node_b, hn_b);

  gather_k<<<16384, 256, 0, stream>>>(hn_f0, node_f0, adjpre4, adj_b, (float*)d_out);
}

// Round 8
// 442.673 us; speedup vs baseline: 1.3513x; 1.0633x over previous
//
#include <hip/hip_runtime.h>
#include <hip/hip_bf16.h>

// GCN_55602646614506 — round 8.
// Single lever vs r7: T2 LDS bank-conflict swizzle on all MFMA GEMMs.
// r7's ds_read_b128 pattern: 16 lanes (same lg) read rows r..r+15 at identical
// 16B col-granule -> same bank (16-way). Fix (rule #21, both-sides): LDS linear,
// global SOURCE granule XOR'd at stage time (sg = g ^ (row&7)), ds_read applies
// the same XOR ((ks*4+lg) ^ (lr&7)). Involution -> bijective. 16-way -> 2-way (free).

typedef __attribute__((ext_vector_type(4))) float  f32x4;
typedef __attribute__((ext_vector_type(8))) __bf16 bf16x8;
typedef __attribute__((ext_vector_type(4))) __bf16 bf16x4;

#define FEPS 1e-10f
#define LNEPS 1e-5f
#define GAMA_F 0.9f

__device__ __forceinline__ void gload16(const void* g, void* l) {
  __builtin_amdgcn_global_load_lds(
      (const __attribute__((address_space(1))) void*)g,
      (__attribute__((address_space(3))) void*)l, 16, 0, 0);
}

__device__ __forceinline__ float read_dim(const void* p) {
  int iv = *(const int*)p;
  if (iv > 0 && iv < (1 << 20)) return (float)iv;
  return *(const float*)p;
}

// ---------------- prep_mega (unchanged) ----------------
__global__ void prep_mega(const float* __restrict__ w1, const float* __restrict__ w2,
                          const float* __restrict__ w3, const float* __restrict__ spw3,
                          const float* __restrict__ spw1, const float* __restrict__ spw2,
                          const float* __restrict__ b3,
                          const float* __restrict__ node_in,
                          const float* __restrict__ coords,
                          const void* __restrict__ imh, const void* __restrict__ imw,
                          __bf16* __restrict__ W1at, __bf16* __restrict__ W1bt,
                          __bf16* __restrict__ W2t, __bf16* __restrict__ W3t,
                          __bf16* __restrict__ SpW3t,
                          __bf16* __restrict__ SpW1t, __bf16* __restrict__ SpW2t,
                          float* __restrict__ b3s,
                          float* __restrict__ node_f, __bf16* __restrict__ node_b,
                          float* __restrict__ hn_f, __bf16* __restrict__ hn_b,
                          __bf16* __restrict__ f36) {
  __shared__ float tile[64][65];
  const int b = blockIdx.x, t = threadIdx.x;
  const int tc = t & 63, tr = t >> 6;
  if (b < 256) {
    const int c = b >> 4, d0 = (b & 15) << 6;
    #pragma unroll
    for (int pass = 0; pass < 2; ++pass) {
      const float* src = w1 + (size_t)c * 131072 + (size_t)(d0 + pass * 1024) * 64;
      __bf16* dst = pass ? W1bt : W1at;
      if (pass) __syncthreads();
      #pragma unroll
      for (int q = 0; q < 16; ++q) {
        int dd = q * 4 + tr;
        tile[dd][tc] = src[dd * 64 + tc];
      }
      __syncthreads();
      #pragma unroll
      for (int q = 0; q < 16; ++q) {
        int kk = q * 4 + tr;
        dst[(size_t)(c * 64 + kk) * 1024 + d0 + tc] = (__bf16)tile[tc][kk];
      }
    }
  } else if (b < 512) {
    const int bb = b - 256, c = bb >> 4, s0 = (bb & 15) << 6;
    const float* src = w2 + (size_t)c * 65536 + (size_t)s0 * 64;
    #pragma unroll
    for (int q = 0; q < 16; ++q) {
      int ss = q * 4 + tr;
      tile[ss][tc] = src[ss * 64 + tc];
    }
    __syncthreads();
    #pragma unroll
    for (int q = 0; q < 16; ++q) {
      int kk = q * 4 + tr;
      W2t[(size_t)(c * 64 + kk) * 1024 + s0 + tc] = (__bf16)tile[tc][kk];
    }
  } else if (b < 768) {
    const int bb = b - 512, c = bb >> 4, o0 = (bb & 15) << 6;
    const float* src = w3 + (size_t)c * 65536;
    #pragma unroll
    for (int q = 0; q < 16; ++q) {
      int kk = q * 4 + tr;
      tile[kk][tc] = src[kk * 1024 + o0 + tc];
    }
    __syncthreads();
    #pragma unroll
    for (int q = 0; q < 16; ++q) {
      int oo = q * 4 + tr;
      W3t[(size_t)(o0 + oo) * 1024 + c * 64 + tc] = (__bf16)tile[tc][oo];
    }
  } else if (b < 832) {
    const int bb = b - 768, o0 = (bb >> 2) << 6, k0 = (bb & 3) << 6;
    #pragma unroll
    for (int q = 0; q < 16; ++q) {
      int kk = q * 4 + tr;
      tile[kk][tc] = spw3[(size_t)(k0 + kk) * 1024 + o0 + tc];
    }
    __syncthreads();
    #pragma unroll
    for (int q = 0; q < 16; ++q) {
      int oo = q * 4 + tr;
      SpW3t[(size_t)(o0 + oo) * 256 + k0 + tc] = (__bf16)tile[tc][oo];
    }
  } else if (b < 960) {
    int gid = (b - 832) * 256 + t;
    if (gid < 8192) {
      int n = gid >> 6, k = gid & 63;
      SpW1t[gid] = (k < 36) ? (__bf16)spw1[k * 128 + n] : (__bf16)0.f;
    }
    {
      int n = gid >> 7, k = gid & 127;
      SpW2t[gid] = (__bf16)spw2[k * 256 + n];
    }
    if (gid < 1024) {
      float s = 0.f;
      for (int cc = 0; cc < 16; ++cc) s += b3[cc * 1024 + gid];
      b3s[gid] = s;
    }
  } else if (b < 3008) {
    int gid = (b - 960) * 256 + t;
    float v = node_in[gid];
    node_f[gid] = v;
    node_b[gid] = (__bf16)v;
    if (gid < 32 * 1024) { hn_f[gid] = v; hn_b[gid] = (__bf16)v; }
  } else {
    int p = (b - 3008) * 256 + t;
    int i = p >> 9, j = p & 511;
    float H = read_dim(imh), W = read_dim(imw);
    f32x4 b1 = ((const f32x4*)coords)[i];
    f32x4 b2 = ((const f32x4*)coords)[j];
    float c1x = (b1[0] + b1[2]) * 0.5f, c1y = (b1[1] + b1[3]) * 0.5f;
    float c2x = (b2[0] + b2[2]) * 0.5f, c2y = (b2[1] + b2[3]) * 0.5f;
    float b1w = b1[2] - b1[0], b1h = b1[3] - b1[1];
    float b2w = b2[2] - b2[0], b2h = b2[3] - b2[1];
    float dx = fabsf(c2x - c1x) / (b1w + FEPS);
    float dy = fabsf(c2y - c1y) / (b1h + FEPS);
    float ltx = fmaxf(b1[0], b2[0]), lty = fmaxf(b1[1], b2[1]);
    float rbx = fminf(b1[2], b2[2]), rby = fminf(b1[3], b2[3]);
    float inter = fmaxf(rbx - ltx, 0.f) * fmaxf(rby - lty, 0.f);
    float a1 = b1w * b1h, a2 = b2w * b2h;
    float iou = inter / (a1 + a2 - inter);
    float f[18];
    f[0] = c1x / W;  f[1] = c1y / H;  f[2] = c2x / W;  f[3] = c2y / H;
    f[4] = b1w / W;  f[5] = b1h / H;  f[6] = b2w / W;  f[7] = b2h / H;
    f[8] = a1 / (H * W); f[9] = a2 / (H * W); f[10] = a2 / (a1 + FEPS);
    f[11] = b1w / (b1h + FEPS); f[12] = b2w / (b2h + FEPS); f[13] = iou;
    f[14] = (c2x > c1x) ? dx : 0.f; f[15] = (c2x < c1x) ? dx : 0.f;
    f[16] = (c2y > c1y) ? dy : 0.f; f[17] = (c2y < c1y) ? dy : 0.f;
    __bf16 o[64];
    #pragma unroll
    for (int q = 0; q < 18; ++q) { o[q] = (__bf16)f[q]; o[18 + q] = (__bf16)logf(f[q] + FEPS); }
    #pragma unroll
    for (int q = 36; q < 64; ++q) o[q] = (__bf16)0.f;
    bf16x8* dst = (bf16x8*)(f36 + (size_t)p * 64);
    #pragma unroll
    for (int q = 0; q < 8; ++q) dst[q] = *(bf16x8*)&o[q * 8];
  }
}

// ---------------- mlp_head (unchanged from r7-fixed) ----------------
__global__ __launch_bounds__(256)
void mlp_head(const __bf16* __restrict__ f36, const __bf16* __restrict__ SpW1t,
              const __bf16* __restrict__ SpW2t, const float* __restrict__ b1,
              const float* __restrict__ b2, __bf16* __restrict__ sp2out) {
  __shared__ __align__(16) __bf16 Af[64 * 64];
  __shared__ __align__(16) __bf16 S1[64 * 128];
  const int t = threadIdx.x;
  const int lane = t & 63, wv = t >> 6;
  const int wr = wv >> 1, wc = wv & 1;
  const int lr = lane & 15, lg = lane >> 4;
  const int m0 = blockIdx.x * 64;

  gload16(f36 + (size_t)m0 * 64 + t * 8, &Af[t * 8]);
  gload16(f36 + (size_t)m0 * 64 + 2048 + t * 8, &Af[2048 + t * 8]);
  __syncthreads();

  {
    f32x4 acc[2][4] = {};
    #pragma unroll
    for (int ks = 0; ks < 2; ++ks) {
      bf16x8 af[2], bf[4];
      #pragma unroll
      for (int mi = 0; mi < 2; ++mi)
        af[mi] = *(const bf16x8*)&Af[(wr * 32 + mi * 16 + lr) * 64 + ks * 32 + lg * 8];
      #pragma unroll
      for (int ni = 0; ni < 4; ++ni)
        bf[ni] = *(const bf16x8*)(SpW1t + (size_t)(wc * 64 + ni * 16 + lr) * 64 + ks * 32 + lg * 8);
      #pragma unroll
      for (int mi = 0; mi < 2; ++mi)
        #pragma unroll
        for (int ni = 0; ni < 4; ++ni)
          acc[mi][ni] = __builtin_amdgcn_mfma_f32_16x16x32_bf16(af[mi], bf[ni], acc[mi][ni], 0, 0, 0);
    }
    #pragma unroll
    for (int mi = 0; mi < 2; ++mi)
      #pragma unroll
      for (int r = 0; r < 4; ++r) {
        int R = wr * 32 + mi * 16 + lg * 4 + r;
        #pragma unroll
        for (int ni = 0; ni < 4; ++ni) {
          int Cc = wc * 64 + ni * 16 + lr;
          S1[R * 128 + Cc] = (__bf16)fmaxf(acc[mi][ni][r] + b1[Cc], 0.f);
        }
      }
  }
  __syncthreads();

  {
    f32x4 acc[2][8] = {};
    #pragma unroll
    for (int ks = 0; ks < 4; ++ks) {
      bf16x8 af[2];
      #pragma unroll
      for (int mi = 0; mi < 2; ++mi)
        af[mi] = *(const bf16x8*)&S1[(wr * 32 + mi * 16 + lr) * 128 + ks * 32 + lg * 8];
      #pragma unroll
      for (int ni = 0; ni < 8; ++ni) {
        bf16x8 bf = *(const bf16x8*)(SpW2t + (size_t)(wc * 128 + ni * 16 + lr) * 128 + ks * 32 + lg * 8);
        #pragma unroll
        for (int mi = 0; mi < 2; ++mi)
          acc[mi][ni] = __builtin_amdgcn_mfma_f32_16x16x32_bf16(af[mi], bf, acc[mi][ni], 0, 0, 0);
      }
    }
    #pragma unroll
    for (int mi = 0; mi < 2; ++mi)
      #pragma unroll
      for (int r = 0; r < 4; ++r) {
        int R = m0 + wr * 32 + mi * 16 + lg * 4 + r;
        #pragma unroll
        for (int ni = 0; ni < 8; ++ni) {
          int Cc = wc * 128 + ni * 16 + lr;
          sp2out[(size_t)R * 256 + Cc] = (__bf16)fmaxf(acc[mi][ni][r] + b2[Cc], 0.f);
        }
      }
  }
}

// ---------------- gemm_bt 128^2 (spb, K=256), XCD swizzle + T2 granule swizzle ----------------
template <int EPI>
__global__ __launch_bounds__(256)
void gemm_bt(const __bf16* __restrict__ A, const __bf16* __restrict__ Bt,
             const float* __restrict__ bias, void* __restrict__ C,
             int N, int K) {
  __shared__ __align__(16) __bf16 As[128 * 64];
  __shared__ __align__(16) __bf16 Bs[128 * 64];
  const int t = threadIdx.x;
  const int lane = t & 63, wv = t >> 6;
  const int wr = wv >> 1, wc = wv & 1;
  const int lr = lane & 15, lg = lane >> 4;
  const int lrow = lane >> 3;
  const int sg = ((lane & 7) ^ (lrow & 7)) << 3;   // T2: swizzled source granule
  const int rxor = (lr & 7);                       // read-side XOR key
  const int b = blockIdx.x;
  const int xcd = b & 7, seq = b >> 3;
  const int m0 = (xcd * 16 + (seq >> 3)) * 128;
  const int n0 = (seq & 7) * 128;

  f32x4 acc[4][4] = {};
  const int nkt = K >> 6;
  for (int kt = 0; kt < nkt; ++kt) {
    const int k0 = kt << 6;
    #pragma unroll
    for (int it = 0; it < 4; ++it) {
      const int rbase = wv * 32 + it * 8;
      gload16(A + (size_t)(m0 + rbase + lrow) * K + k0 + sg, &As[rbase * 64]);
      gload16(Bt + (size_t)(n0 + rbase + lrow) * K + k0 + sg, &Bs[rbase * 64]);
    }
    __syncthreads();
    #pragma unroll
    for (int ks = 0; ks < 2; ++ks) {
      bf16x8 af[4], bfr[4];
      #pragma unroll
      for (int mi = 0; mi < 4; ++mi)
        af[mi] = *(const bf16x8*)&As[(wr * 64 + mi * 16 + lr) * 64 + (((ks * 4 + lg) ^ rxor) << 3)];
      #pragma unroll
      for (int ni = 0; ni < 4; ++ni)
        bfr[ni] = *(const bf16x8*)&Bs[(wc * 64 + ni * 16 + lr) * 64 + (((ks * 4 + lg) ^ rxor) << 3)];
      #pragma unroll
      for (int mi = 0; mi < 4; ++mi)
        #pragma unroll
        for (int ni = 0; ni < 4; ++ni)
          acc[mi][ni] = __builtin_amdgcn_mfma_f32_16x16x32_bf16(af[mi], bfr[ni], acc[mi][ni], 0, 0, 0);
    }
    __syncthreads();
  }
  #pragma unroll
  for (int mi = 0; mi < 4; ++mi)
    #pragma unroll
    for (int r = 0; r < 4; ++r) {
      int R = m0 + wr * 64 + mi * 16 + lg * 4 + r;
      #pragma unroll
      for (int ni = 0; ni < 4; ++ni) {
        int Cc = n0 + wc * 64 + ni * 16 + lr;
        float v = acc[mi][ni][r] + bias[Cc];
        if constexpr (EPI == 0) v = fmaxf(v, 0.f);
        ((__bf16*)C)[(size_t)R * N + Cc] = (__bf16)v;
      }
    }
}

// ---------------- gemm256: 256^2 8-phase-lite + T2 granule swizzle ----------------
template <int EPI>
__global__ __launch_bounds__(512, 2)
void gemm256(const __bf16* __restrict__ A, const __bf16* __restrict__ Bt,
             const float* __restrict__ bias, void* __restrict__ C,
             const float* __restrict__ adjw, float* __restrict__ adjpre4,
             int K) {
  __shared__ __align__(16) __bf16 As[2][256 * 64];
  __shared__ __align__(16) __bf16 Bs[2][256 * 64];
  __shared__ float redbuf[4][256];
  const int t = threadIdx.x;
  const int lane = t & 63;
  const int wv = t >> 6;
  const int wm = wv >> 2, wn = wv & 3;
  const int lr = lane & 15, lg = lane >> 4;
  const int b = blockIdx.x;
  const int xcd = b & 7, seq = b >> 3;
  const int m0 = (xcd * 8 + (seq >> 2)) * 256;
  const int n0 = (seq & 3) * 256;
  const int srow = t >> 3, scol = (t & 7) * 8;
  const int sg = (((t & 7) ^ (srow & 7)) << 3);    // T2 swizzled source granule
  const int rxor = (lr & 7);

  f32x4 acc[8][4] = {};
  const int nkt = K >> 6;

  #pragma unroll
  for (int c = 0; c < 4; ++c) {
    gload16(A + (size_t)(m0 + c * 64 + srow) * K + sg, &As[0][(c * 64 + srow) * 64 + scol]);
    gload16(Bt + (size_t)(n0 + c * 64 + srow) * K + sg, &Bs[0][(c * 64 + srow) * 64 + scol]);
  }
  asm volatile("s_waitcnt vmcnt(0)" ::: "memory");
  __builtin_amdgcn_s_barrier();
  __builtin_amdgcn_sched_barrier(0);

  int cur = 0;
  for (int kt = 0; kt < nkt; ++kt) {
    const int k1 = (kt + 1) << 6;
    const __bf16* Acur = &As[cur][0];
    const __bf16* Bcur = &Bs[cur][0];
    __bf16* Anxt = &As[cur ^ 1][0];
    __bf16* Bnxt = &Bs[cur ^ 1][0];
    const bool more = (kt + 1 < nkt);
    bf16x8 bfr[4][2];
    #pragma unroll
    for (int p = 0; p < 4; ++p) {
      bf16x8 af[2][2];
      #pragma unroll
      for (int m = 0; m < 2; ++m) {
        const int row = wm * 128 + (2 * p + m) * 16 + lr;
        af[m][0] = *(const bf16x8*)&Acur[row * 64 + ((lg ^ rxor) << 3)];
        af[m][1] = *(const bf16x8*)&Acur[row * 64 + (((4 + lg) ^ rxor) << 3)];
      }
      if (p == 0) {
        #pragma unroll
        for (int n = 0; n < 4; ++n) {
          const int row = wn * 64 + n * 16 + lr;
          bfr[n][0] = *(const bf16x8*)&Bcur[row * 64 + ((lg ^ rxor) << 3)];
          bfr[n][1] = *(const bf16x8*)&Bcur[row * 64 + (((4 + lg) ^ rxor) << 3)];
        }
      }
      if (more && p < 2) {
        #pragma unroll
        for (int cc = 0; cc < 2; ++cc) {
          const int c = p * 2 + cc;
          gload16(A + (size_t)(m0 + c * 64 + srow) * K + k1 + sg, &Anxt[(c * 64 + srow) * 64 + scol]);
          gload16(Bt + (size_t)(n0 + c * 64 + srow) * K + k1 + sg, &Bnxt[(c * 64 + srow) * 64 + scol]);
        }
      }
      __builtin_amdgcn_s_barrier();
      __builtin_amdgcn_s_setprio(1);
      #pragma unroll
      for (int ks = 0; ks < 2; ++ks)
        #pragma unroll
        for (int m = 0; m < 2; ++m)
          #pragma unroll
          for (int n = 0; n < 4; ++n)
            acc[2 * p + m][n] = __builtin_amdgcn_mfma_f32_16x16x32_bf16(
                af[m][ks], bfr[n][ks], acc[2 * p + m][n], 0, 0, 0);
      __builtin_amdgcn_s_setprio(0);
      __builtin_amdgcn_s_barrier();
    }
    if (more) {
      asm volatile("s_waitcnt vmcnt(0)" ::: "memory");
      __builtin_amdgcn_s_barrier();
      __builtin_amdgcn_sched_barrier(0);
    }
    cur ^= 1;
  }

  if constexpr (EPI == 1) {
    #pragma unroll
    for (int mi = 0; mi < 8; ++mi)
      #pragma unroll
      for (int r = 0; r < 4; ++r) {
        const int R = m0 + wm * 128 + mi * 16 + lg * 4 + r;
        #pragma unroll
        for (int ni = 0; ni < 4; ++ni) {
          const int Cc = n0 + wn * 64 + ni * 16 + lr;
          ((__bf16*)C)[(size_t)R * 1024 + Cc] = (__bf16)(acc[mi][ni][r] + bias[Cc]);
        }
      }
  } else {
    float b3v[4], awv[4];
    #pragma unroll
    for (int ni = 0; ni < 4; ++ni) {
      const int Cc = n0 + wn * 64 + ni * 16 + lr;
      b3v[ni] = bias[Cc];
      awv[ni] = adjw[Cc];
    }
    #pragma unroll
    for (int mi = 0; mi < 8; ++mi)
      #pragma unroll
      for (int r = 0; r < 4; ++r) {
        float s = 0.f;
        #pragma unroll
        for (int ni = 0; ni < 4; ++ni)
          s += fmaxf(acc[mi][ni][r] + b3v[ni], 0.f) * awv[ni];
        s += __shfl_xor(s, 1);
        s += __shfl_xor(s, 2);
        s += __shfl_xor(s, 4);
        s += __shfl_xor(s, 8);
        if (lr == 0)
          redbuf[wn][wm * 128 + mi * 16 + lg * 4 + r] = s;
      }
    __syncthreads();
    if (t < 256) {
      const int h = seq & 3;
      adjpre4[(size_t)h * 16384 + m0 + t] =
          redbuf[0][t] + redbuf[1][t] + redbuf[2][t] + redbuf[3][t];
    }
  }
}

// ---------------- gemm_u1 (T2 swizzled) ----------------
__global__ __launch_bounds__(256)
void gemm_u1(const __bf16* __restrict__ hn_b, const __bf16* __restrict__ node_b,
             const __bf16* __restrict__ W1at, const __bf16* __restrict__ W1bt,
             const float* __restrict__ b1, float* __restrict__ H1, float* __restrict__ N1) {
  __shared__ __align__(16) __bf16 As[32 * 64];
  __shared__ __align__(16) __bf16 Bs[128 * 64];
  const int t = threadIdx.x;
  const int lane = t & 63, wv = t >> 6;
  const int wr = wv >> 1, wc = wv & 1;
  const int lr = lane & 15, lg = lane >> 4;
  const int lrow = lane >> 3;
  const int sg = ((lane & 7) ^ (lrow & 7)) << 3;
  const int rxor = (lr & 7);
  const bool isH = (blockIdx.x == 0);
  const __bf16* Ap = isH ? hn_b : node_b + (size_t)(blockIdx.x - 1) * 32 * 1024;
  const __bf16* Bp = isH ? W1at : W1bt;
  const int n0 = blockIdx.y * 128;

  f32x4 acc[4] = {};
  for (int kt = 0; kt < 16; ++kt) {
    const int k0 = kt << 6;
    gload16(Ap + (size_t)(wv * 8 + lrow) * 1024 + k0 + sg, &As[(wv * 8) * 64]);
    #pragma unroll
    for (int it = 0; it < 4; ++it) {
      const int rbase = wv * 32 + it * 8;
      gload16(Bp + (size_t)(n0 + rbase + lrow) * 1024 + k0 + sg, &Bs[rbase * 64]);
    }
    __syncthreads();
    #pragma unroll
    for (int ks = 0; ks < 2; ++ks) {
      bf16x8 af = *(const bf16x8*)&As[(wr * 16 + lr) * 64 + (((ks * 4 + lg) ^ rxor) << 3)];
      #pragma unroll
      for (int ni = 0; ni < 4; ++ni) {
        bf16x8 bfr = *(const bf16x8*)&Bs[(wc * 64 + ni * 16 + lr) * 64 + (((ks * 4 + lg) ^ rxor) << 3)];
        acc[ni] = __builtin_amdgcn_mfma_f32_16x16x32_bf16(af, bfr, acc[ni], 0, 0, 0);
      }
    }
    __syncthreads();
  }
  #pragma unroll
  for (int ni = 0; ni < 4; ++ni)
    #pragma unroll
    for (int r = 0; r < 4; ++r) {
      int R = wr * 16 + lg * 4 + r;
      int Cc = n0 + wc * 64 + ni * 16 + lr;
      float v = acc[ni][r];
      if (isH) H1[(size_t)R * 1024 + Cc] = v + b1[Cc];
      else     N1[((size_t)(blockIdx.x - 1) * 32 + R) * 1024 + Cc] = v;
    }
}

// ---------------- build_hdn (unchanged) ----------------
__global__ void build_hdn(const __bf16* __restrict__ u2, const float* __restrict__ H1,
                          const float* __restrict__ N1, __bf16* __restrict__ hdn) {
  int gid = blockIdx.x * 256 + threadIdx.x;
  int p = gid >> 7, c8 = (gid & 127) << 3;
  int i = p >> 9, j = p & 511;
  bf16x8 u = *(const bf16x8*)(u2 + (size_t)p * 1024 + c8);
  const float* hp = H1 + (size_t)i * 1024 + c8;
  const float* np = N1 + (size_t)j * 1024 + c8;
  f32x4 h0 = *(const f32x4*)hp, h1 = *(const f32x4*)(hp + 4);
  f32x4 n0 = *(const f32x4*)np, n1 = *(const f32x4*)(np + 4);
  bf16x8 o;
  #pragma unroll
  for (int e = 0; e < 4; ++e) {
    o[e]     = (__bf16)fmaxf((h0[e] + n0[e]) * (float)u[e], 0.f);
    o[4 + e] = (__bf16)fmaxf((h1[e] + n1[e]) * (float)u[4 + e], 0.f);
  }
  *(bf16x8*)(hdn + (size_t)p * 1024 + c8) = o;
}

// ---------------- msgln (unchanged) ----------------
__global__ void msgln(const float* __restrict__ adjpre4, const float* __restrict__ adjb,
                      const float* __restrict__ node_in_f, const float* __restrict__ hn_in_f,
                      const float* __restrict__ lno_g, const float* __restrict__ lno_b,
                      const float* __restrict__ lnh_g, const float* __restrict__ lnh_b,
                      float* __restrict__ node_out_f, float* __restrict__ hn_out_f,
                      __bf16* __restrict__ node_bb, __bf16* __restrict__ hn_bb) {
  __shared__ float adjrow[512];
  __shared__ float sbuf[4];
  const int row = blockIdx.x, t = threadIdx.x;
  const float ab = adjb[0];
  const bool isH = row < 32;
  f32x4 msg = {0.f, 0.f, 0.f, 0.f};
  if (isH) {
    const int i = row;
    float s0 = 0.f, s1 = 0.f;
    #pragma unroll
    for (int h = 0; h < 4; ++h) {
      s0 += adjpre4[(size_t)h * 16384 + i * 512 + t];
      s1 += adjpre4[(size_t)h * 16384 + i * 512 + 256 + t];
    }
    adjrow[t] = fmaxf(s0 + ab, 0.f);
    adjrow[256 + t] = fmaxf(s1 + ab, 0.f);
    __syncthreads();
    for (int j = 0; j < 512; ++j)
      msg += adjrow[j] * ((const f32x4*)node_in_f)[j * 256 + t];
  } else {
    const int j = row - 32;
    int i = t >> 3, hh = t & 7;
    float v = (hh < 4) ? adjpre4[(size_t)hh * 16384 + i * 512 + j] : 0.f;
    v += __shfl_xor(v, 1);
    v += __shfl_xor(v, 2);
    v += __shfl_xor(v, 4);
    if (hh == 0) adjrow[i] = fmaxf(v + ab, 0.f);
    __syncthreads();
    for (int i2 = 0; i2 < 32; ++i2)
      msg += adjrow[i2] * ((const f32x4*)hn_in_f)[i2 * 256 + t];
  }
  const int r = isH ? row : row - 32;
  const float* X = (isH ? hn_in_f : node_in_f) + (size_t)r * 1024;
  const float* g = isH ? lnh_g : lno_g;
  const float* bb = isH ? lnh_b : lno_b;
  float* Xo = (isH ? hn_out_f : node_out_f) + (size_t)r * 1024;
  __bf16* Xb = (isH ? hn_bb : node_bb) + (size_t)r * 1024;

  f32x4 x = ((const f32x4*)X)[t];
  f32x4 y;
  #pragma unroll
  for (int e = 0; e < 4; ++e) y[e] = x[e] * GAMA_F + (1.0f - GAMA_F) * msg[e];
  float s = y[0] + y[1] + y[2] + y[3];
  #pragma unroll
  for (int mm = 32; mm >= 1; mm >>= 1) s += __shfl_xor(s, mm);
  if ((t & 63) == 0) sbuf[t >> 6] = s;
  __syncthreads();
  float mean = (sbuf[0] + sbuf[1] + sbuf[2] + sbuf[3]) * (1.0f / 1024.0f);
  __syncthreads();
  f32x4 d;
  #pragma unroll
  for (int e = 0; e < 4; ++e) d[e] = y[e] - mean;
  float sq = d[0] * d[0] + d[1] * d[1] + d[2] * d[2] + d[3] * d[3];
  #pragma unroll
  for (int mm = 32; mm >= 1; mm >>= 1) sq += __shfl_xor(sq, mm);
  if ((t & 63) == 0) sbuf[t >> 6] = sq;
  __syncthreads();
  float var = (sbuf[0] + sbuf[1] + sbuf[2] + sbuf[3]) * (1.0f / 1024.0f);
  float inv = rsqrtf(var + LNEPS);
  f32x4 gg = ((const f32x4*)g)[t];
  f32x4 bv = ((const f32x4*)bb)[t];
  f32x4 o;
  bf16x4 ob;
  #pragma unroll
  for (int e = 0; e < 4; ++e) { o[e] = d[e] * inv * gg[e] + bv[e]; ob[e] = (__bf16)o[e]; }
  ((f32x4*)Xo)[t] = o;
  *(bf16x4*)(Xb + t * 4) = ob;
}

// ---------------- gather (unchanged) ----------------
__global__ void gather_k(const float* __restrict__ hn, const float* __restrict__ node,
                         const float* __restrict__ adjpre4, const float* __restrict__ adjb,
                         float* __restrict__ out) {
  int p = blockIdx.x, t = threadIdx.x;
  int i = p >> 9, j = p & 511;
  if (i == j) return;
  int m = p - (p + 512) / 513;
  float* out0 = out;
  float* out1 = out + (size_t)16352 * 1024;
  float* out2 = out1 + (size_t)16352 * 1024;
  ((f32x4*)out0)[(size_t)m * 256 + t] = ((const f32x4*)hn)[i * 256 + t];
  ((f32x4*)out1)[(size_t)m * 256 + t] = ((const f32x4*)node)[j * 256 + t];
  if (t == 0) {
    float s = adjb[0];
    #pragma unroll
    for (int h = 0; h < 4; ++h) s += adjpre4[(size_t)h * 16384 + p];
    out2[m] = fmaxf(s, 0.f);
    out2[16352 + m] = (float)i;
    out2[2 * 16352 + m] = (float)j;
  }
}

// ---------------- host ----------------
extern "C" void kernel_launch(void* const* d_in, const int* in_sizes, int n_in,
                              void* d_out, int out_size, void* d_ws, size_t ws_size,
                              hipStream_t stream) {
  const float* node_in = (const float*)d_in[1];
  const float* coords  = (const float*)d_in[2];
  const void*  imh     = d_in[3];
  const void*  imw     = d_in[4];
  const float* sp_w1 = (const float*)d_in[5];
  const float* sp_b1 = (const float*)d_in[6];
  const float* sp_w2 = (const float*)d_in[7];
  const float* sp_b2 = (const float*)d_in[8];
  const float* sp_w3 = (const float*)d_in[9];
  const float* sp_b3 = (const float*)d_in[10];
  const float* att_w1 = (const float*)d_in[11];
  const float* att_b1 = (const float*)d_in[12];
  const float* att_w2 = (const float*)d_in[13];
  const float* att_b2 = (const float*)d_in[14];
  const float* att_w3 = (const float*)d_in[15];
  const float* att_b3 = (const float*)d_in[16];
  const float* adj_w  = (const float*)d_in[17];
  const float* adj_b  = (const float*)d_in[18];
  const float* lnh_g  = (const float*)d_in[19];
  const float* lnh_b  = (const float*)d_in[20];
  const float* lno_g  = (const float*)d_in[21];
  const float* lno_b  = (const float*)d_in[22];

  char* w = (char*)d_ws;
  size_t off = 0;
  auto alloc = [&](size_t bytes) -> char* {
    char* p = w + off;
    off += (bytes + 255) & ~(size_t)255;
    return p;
  };
  __bf16* W1at  = (__bf16*)alloc((size_t)1024 * 1024 * 2);
  __bf16* W1bt  = (__bf16*)alloc((size_t)1024 * 1024 * 2);
  __bf16* W2t   = (__bf16*)alloc((size_t)1024 * 1024 * 2);
  __bf16* W3t   = (__bf16*)alloc((size_t)1024 * 1024 * 2);
  __bf16* SpW1t = (__bf16*)alloc(128 * 64 * 2);
  __bf16* SpW2t = (__bf16*)alloc(256 * 128 * 2);
  __bf16* SpW3t = (__bf16*)alloc(1024 * 256 * 2);
  float*  b3s   = (float*)alloc(1024 * 4);
  __bf16* f36   = (__bf16*)alloc((size_t)16384 * 64 * 2);
  __bf16* sp2   = (__bf16*)alloc((size_t)16384 * 256 * 2);
  __bf16* spb   = (__bf16*)alloc((size_t)16384 * 1024 * 2);  // reused as hdn after u2
  __bf16* u2    = (__bf16*)alloc((size_t)16384 * 1024 * 2);
  float*  H1    = (float*)alloc((size_t)32 * 1024 * 4);
  float*  N1    = (float*)alloc((size_t)512 * 1024 * 4);
  float*  adjpre4 = (float*)alloc((size_t)4 * 16384 * 4);
  float*  node_f0 = (float*)alloc((size_t)512 * 1024 * 4);
  float*  node_f1 = (float*)alloc((size_t)512 * 1024 * 4);
  float*  hn_f0   = (float*)alloc((size_t)32 * 1024 * 4);
  float*  hn_f1   = (float*)alloc((size_t)32 * 1024 * 4);
  __bf16* node_b  = (__bf16*)alloc((size_t)512 * 1024 * 2);
  __bf16* hn_b    = (__bf16*)alloc((size_t)32 * 1024 * 2);
  if (off > ws_size) return;  // fail loud rather than corrupt

  prep_mega<<<3072, 256, 0, stream>>>(att_w1, att_w2, att_w3, sp_w3, sp_w1, sp_w2, att_b3,
                                      node_in, coords, imh, imw,
                                      W1at, W1bt, W2t, W3t, SpW3t, SpW1t, SpW2t, b3s,
                                      node_f0, node_b, hn_f0, hn_b, f36);
  mlp_head<<<256, 256, 0, stream>>>(f36, SpW1t, SpW2t, sp_b1, sp_b2, sp2);
  gemm_bt<0><<<1024, 256, 0, stream>>>(sp2, SpW3t, sp_b3, spb, 1024, 256);
  gemm256<1><<<256, 512, 0, stream>>>(spb, W2t, att_b2, u2, nullptr, nullptr, 1024);

  __bf16* hdn = spb;  // spb dead after u2
  // iter 1: read f0 -> write f1
  gemm_u1<<<dim3(17, 8), 256, 0, stream>>>(hn_b, node_b, W1at, W1bt, att_b1, H1, N1);
  build_hdn<<<8192, 256, 0, stream>>>(u2, H1, N1, hdn);
  gemm256<4><<<256, 512, 0, stream>>>(hdn, W3t, b3s, nullptr, adj_w, adjpre4, 1024);
  msgln<<<544, 256, 0, stream>>>(adjpre4, adj_b, node_f0, hn_f0,
                                 lno_g, lno_b, lnh_g, lnh_b,
                                 node_f1, hn_f1, node_b, hn_b);
  // iter 2: read f1 -> write f0
  gemm_u1<<<dim3(17, 8), 256, 0, stream>>>(hn_b, node_b, W1at, W1bt, att_b1, H1, N1);
  build_hdn<<<8192, 256, 0, stream>>>(u2, H1, N1, hdn);
  gemm256<4><<<256, 512, 0, stream>>>(hdn, W3t, b3s, nullptr, adj_w, adjpre4, 1024);
  msgln<<<544, 256, 0, stream>>>(adjpre4, adj_b, node_f1, hn_f1,
                                 lno_g, lno_b, lnh_g, lnh_b,
                                 node_f0, hn_f0, node_b, hn_b);

  gather_k<<<16384, 256, 0, stream>>>(hn_f0, node_f0, adjpre4, adj_b, (float*)d_out);
}